// Round 7
// baseline (732.137 us; speedup 1.0000x reference)
//
#include <hip/hip_runtime.h>
#include <hip/hip_cooperative_groups.h>
#include <math.h>

namespace cg = cooperative_groups;

#define B 32
#define S 512
#define Q 512
#define I 256
#define O 64
#define SIG_EPS 0.1f
#define LOG_SIG_EPS (-2.3025850929940457f)

// f32 workspace offsets
#define WS_L 0
#define WS_T1 65536
#define WS_LKT 81920
#define WS_M0 98304
#define WS_M1 2195456
#define WS_RHST 4292608
#define WS_D 4816896
#define WS_U16 5079040
// u16 offsets (units of u16)
#define U_PTH 0
#define U_PTL 4194304
#define U_YTH 8388608
#define U_YTL 9437184
#define U_IVH 10485760
#define U_IVL 12582912
#define U_PKH 14680064
#define U_PKL 15204352

#define OUT_MU_ELEMS (B * Q * O)
#define OUT_SIG_ELEMS (B * Q * O * O)
#define OUT_NLL_IDX (OUT_MU_ELEMS + OUT_SIG_ELEMS)

typedef short short8 __attribute__((ext_vector_type(8)));
typedef float f32x4 __attribute__((ext_vector_type(4)));
#define MFMA16(a, b, c) __builtin_amdgcn_mfma_f32_16x16x32_bf16(a, b, c, 0, 0, 0)

struct Params {
  const float *phi_s, *y_s, *phi_q, *y_q, *Km, *La;
  float *Lm, *T1, *LKT, *M0, *M1, *RHST, *Dbuf;
  unsigned short *PTh, *PTl, *YTh, *YTl, *IVh, *IVl, *PKh, *PKl;
  float *mu, *nll;
  float4 *sig;
};

__device__ __forceinline__ f32x4 mfma3(short8 ah, short8 al, short8 bh, short8 bl, f32x4 c) {
  c = MFMA16(ah, bh, c);
  c = MFMA16(ah, bl, c);
  c = MFMA16(al, bh, c);
  return c;
}

__device__ __forceinline__ unsigned short f2bf(float x) {
  unsigned int u = __float_as_uint(x);
  return (unsigned short)((u + 0x7fffu + ((u >> 16) & 1u)) >> 16);
}
__device__ __forceinline__ float bf2f(unsigned short h) { return __uint_as_float(((unsigned int)h) << 16); }
__device__ __forceinline__ void split2(float x, unsigned short& h, unsigned short& l) {
  h = f2bf(x);
  l = f2bf(x - bf2f(h));
}
__device__ __forceinline__ void split4(float4 v, uint2& H, uint2& L) {
  unsigned short h0, h1, h2, h3, l0, l1, l2, l3;
  split2(v.x, h0, l0); split2(v.y, h1, l1); split2(v.z, h2, l2); split2(v.w, h3, l3);
  H.x = (unsigned)h0 | ((unsigned)h1 << 16); H.y = (unsigned)h2 | ((unsigned)h3 << 16);
  L.x = (unsigned)l0 | ((unsigned)l1 << 16); L.y = (unsigned)l2 | ((unsigned)l3 << 16);
}
__device__ __forceinline__ void cvt8(const float* p, short8& h8, short8& l8) {
  float4 a = *(const float4*)p;
  float4 b = *(const float4*)(p + 4);
  uint2 H0, L0, H1, L1;
  split4(a, H0, L0); split4(b, H1, L1);
  union { uint2 q[2]; short8 s; } uh, ul;
  uh.q[0] = H0; uh.q[1] = H1; ul.q[0] = L0; ul.q[1] = L1;
  h8 = uh.s; l8 = ul.s;
}
__device__ __forceinline__ short8 ld8(const unsigned short* p) { return *(const short8*)(const void*)p; }

__device__ __forceinline__ void fma4x4(const float4 av, const float4 bv, float acc[4][4]) {
  const float ar[4] = {av.x, av.y, av.z, av.w};
  const float br[4] = {bv.x, bv.y, bv.z, bv.w};
#pragma unroll
  for (int i = 0; i < 4; ++i)
#pragma unroll
    for (int j = 0; j < 4; ++j) acc[i][j] += ar[i] * br[j];
}

__device__ __forceinline__ void load_direct64(float* dst, int ds, const float* src, int ss, int t) {
#pragma unroll
  for (int m = 0; m < 4; ++m) {
    int r = (t >> 4) + 16 * m, c4 = (t & 15) * 4;
    *(float4*)&dst[r * ds + c4] = *(const float4*)&src[(size_t)r * ss + c4];
  }
}
__device__ __forceinline__ void load_trans64(float* dst, int ds, const float* src, int ss, int t) {
#pragma unroll
  for (int m = 0; m < 4; ++m) {
    int r = (t >> 4) + 16 * m, c4 = (t & 15) * 4;
    float4 v = *(const float4*)&src[(size_t)r * ss + c4];
    dst[(c4 + 0) * ds + r] = v.x;
    dst[(c4 + 1) * ds + r] = v.y;
    dst[(c4 + 2) * ds + r] = v.z;
    dst[(c4 + 3) * ds + r] = v.w;
  }
}
template <int SA, int SB>
__device__ __forceinline__ void gemm64(const float* At, const float* Bs, int tr, int tc, float acc[4][4]) {
#pragma unroll 8
  for (int kk = 0; kk < 64; ++kk) {
    float4 a = *(const float4*)&At[kk * SA + tr * 4];
    float4 b = *(const float4*)&Bs[kk * SB + tc * 4];
    fma4x4(a, b, acc);
  }
}

#define SC4(V) V.x *= pivinv; V.y *= pivinv; V.z *= pivinv; V.w *= pivinv
#define UP4(V, R) V.x -= g * R.x; V.y -= g * R.y; V.z -= g * R.z; V.w -= g * R.w

template <int TS>
__device__ void gj64(const float* T, float* rowbuf, float* Dout, int t) {
  int r = t >> 2, q = t & 3;
  int lane = t & 63;
  float4 A0 = *(const float4*)&T[r * TS + q * 16 + 0];
  float4 A1 = *(const float4*)&T[r * TS + q * 16 + 4];
  float4 A2 = *(const float4*)&T[r * TS + q * 16 + 8];
  float4 A3 = *(const float4*)&T[r * TS + q * 16 + 12];
#define IC(c) (((q * 16 + (c)) == r) ? 1.f : 0.f)
  float4 I0 = make_float4(IC(0), IC(1), IC(2), IC(3));
  float4 I1 = make_float4(IC(4), IC(5), IC(6), IC(7));
  float4 I2 = make_float4(IC(8), IC(9), IC(10), IC(11));
  float4 I3 = make_float4(IC(12), IC(13), IC(14), IC(15));
#undef IC
  for (int p = 0; p < 64; ++p) {
    float* RA = rowbuf + (p & 1) * 128;
    float* RI = RA + 64;
    if (r == p) {
      ((float4*)&RA[q * 16])[0] = A0; ((float4*)&RA[q * 16])[1] = A1;
      ((float4*)&RA[q * 16])[2] = A2; ((float4*)&RA[q * 16])[3] = A3;
      ((float4*)&RI[q * 16])[0] = I0; ((float4*)&RI[q * 16])[1] = I1;
      ((float4*)&RI[q * 16])[2] = I2; ((float4*)&RI[q * 16])[3] = I3;
    }
    __syncthreads();
    float pivinv = 1.0f / RA[p];
    int sidx = p & 15;
    float4 blk = (sidx < 8) ? ((sidx < 4) ? A0 : A1) : ((sidx < 12) ? A2 : A3);
    int sc = sidx & 3;
    float ap = (sc == 0) ? blk.x : (sc == 1) ? blk.y : (sc == 2) ? blk.z : blk.w;
    float f = __shfl(ap, (lane & ~3) | (p >> 4), 64);
    float4 ra0 = ((const float4*)&RA[q * 16])[0], ra1 = ((const float4*)&RA[q * 16])[1];
    float4 ra2 = ((const float4*)&RA[q * 16])[2], ra3 = ((const float4*)&RA[q * 16])[3];
    float4 ri0 = ((const float4*)&RI[q * 16])[0], ri1 = ((const float4*)&RI[q * 16])[1];
    float4 ri2 = ((const float4*)&RI[q * 16])[2], ri3 = ((const float4*)&RI[q * 16])[3];
    if (r == p) {
      SC4(A0); SC4(A1); SC4(A2); SC4(A3);
      SC4(I0); SC4(I1); SC4(I2); SC4(I3);
    } else {
      float g = f * pivinv;
      UP4(A0, ra0); UP4(A1, ra1); UP4(A2, ra2); UP4(A3, ra3);
      UP4(I0, ri0); UP4(I1, ri1); UP4(I2, ri2); UP4(I3, ri3);
    }
  }
  ((float4*)&Dout[r * 64 + q * 16])[0] = I0;
  ((float4*)&Dout[r * 64 + q * 16])[1] = I1;
  ((float4*)&Dout[r * 64 + q * 16])[2] = I2;
  ((float4*)&Dout[r * 64 + q * 16])[3] = I3;
}

// ================= phase 0: cvt (w<1280) + pre1 (w in [1280,1300)) =================
__device__ void phase0_unit(const Params& p, int w, int t, float* smem) {
  if (w < 1280) {
    unsigned short* Hs = (unsigned short*)smem;  // [64][68]
    unsigned short* Lo = Hs + 64 * 68;
    const float* src;
    unsigned short *dh, *dl;
    int sstride;
    if (w < 1024) {
      int b = w >> 5, r = w & 31, ic = r >> 3, sc = r & 7;
      src = p.phi_s + ((size_t)b * 512 + sc * 64) * 256 + ic * 64;
      sstride = 256;
      size_t d0 = ((size_t)b * 256 + ic * 64) * 512 + sc * 64;
      dh = p.PTh + d0; dl = p.PTl + d0;
    } else {
      int qq = w - 1024, b = qq >> 3, sc = qq & 7;
      src = p.y_s + ((size_t)b * 512 + sc * 64) * 64;
      sstride = 64;
      size_t d0 = ((size_t)b * 64) * 512 + sc * 64;
      dh = p.YTh + d0; dl = p.YTl + d0;
    }
    int c = t & 63, rb = (t >> 6) * 16;
#pragma unroll
    for (int m = 0; m < 16; ++m) {
      int s = rb + m;
      float x = src[(size_t)s * sstride + c];
      unsigned short h, l;
      split2(x, h, l);
      Hs[c * 68 + s] = h;
      Lo[c * 68 + s] = l;
    }
    __syncthreads();
    int il0 = t >> 4, c4 = (t & 15) * 4;
#pragma unroll
    for (int m = 0; m < 4; ++m) {
      int il = il0 + 16 * m;
      uint2 H, L;
      H.x = (unsigned)Hs[il * 68 + c4] | ((unsigned)Hs[il * 68 + c4 + 1] << 16);
      H.y = (unsigned)Hs[il * 68 + c4 + 2] | ((unsigned)Hs[il * 68 + c4 + 3] << 16);
      L.x = (unsigned)Lo[il * 68 + c4] | ((unsigned)Lo[il * 68 + c4 + 1] << 16);
      L.y = (unsigned)Lo[il * 68 + c4 + 2] | ((unsigned)Lo[il * 68 + c4 + 3] << 16);
      *(uint2*)&dh[(size_t)il * 512 + c4] = H;
      *(uint2*)&dl[(size_t)il * 512 + c4] = L;
    }
  } else {
    int blk2 = w - 1280;
    float* sA = smem;
    float* sB = smem + 1088;
    int tr = t >> 4, tc = t & 15;
    float acc[4][4] = {};
    if (blk2 < 16) {
      int i0 = (blk2 >> 2) * 64, j0 = (blk2 & 3) * 64;
      for (int ks = 0; ks < 256; ks += 16) {
        __syncthreads();
#pragma unroll
        for (int m = 0; m < 4; ++m) {
          int r = (t >> 4) + 16 * m, kk = t & 15;
          sA[kk * 68 + r] = p.La[(size_t)(i0 + r) * 256 + ks + kk];
          sB[kk * 68 + r] = p.La[(size_t)(j0 + r) * 256 + ks + kk];
        }
        __syncthreads();
#pragma unroll
        for (int kk = 0; kk < 16; ++kk) {
          float4 a = *(const float4*)&sA[kk * 68 + tr * 4];
          float4 bv = *(const float4*)&sB[kk * 68 + tc * 4];
          fma4x4(a, bv, acc);
        }
      }
#pragma unroll
      for (int mi = 0; mi < 4; ++mi) {
        float4 v = {acc[mi][0], acc[mi][1], acc[mi][2], acc[mi][3]};
        *(float4*)&p.Lm[(size_t)(i0 + tr * 4 + mi) * 256 + j0 + tc * 4] = v;
      }
    } else {
      int i0 = (blk2 - 16) * 64;
      for (int ks = 0; ks < 256; ks += 16) {
        __syncthreads();
#pragma unroll
        for (int m = 0; m < 4; ++m) {
          int kk = (t >> 6) + 4 * m, c = t & 63;
          sA[kk * 68 + c] = p.La[(size_t)(ks + kk) * 256 + i0 + c];
          sB[kk * 68 + c] = p.Km[(size_t)(ks + kk) * 64 + c];
        }
        __syncthreads();
#pragma unroll
        for (int kk = 0; kk < 16; ++kk) {
          float4 a = *(const float4*)&sA[kk * 68 + tr * 4];
          float4 bv = *(const float4*)&sB[kk * 68 + tc * 4];
          fma4x4(a, bv, acc);
        }
      }
#pragma unroll
      for (int mi = 0; mi < 4; ++mi) {
        float4 v = {acc[mi][0], acc[mi][1], acc[mi][2], acc[mi][3]};
        *(float4*)&p.T1[(size_t)(i0 + tr * 4 + mi) * 64 + tc * 4] = v;
      }
    }
  }
}

// ================= gram: u<10 sym M tiles, u 10-13 RHS, u==14 LK (b<4), u==15 idle =================
__device__ void gram_unit(const Params& p, int b, int u, int t, float* smem) {
  float* trbuf = smem;          // 64*68
  float* Ws = smem + 4352;      // 16*64
  float* rowb = smem + 12800;   // 256
  if (u == 15) return;
  if (u == 14) {
    if (b >= 4) return;
    int i0 = b * 64;
    int tr = t >> 4, tc = t & 15;
    float acc[4][4] = {};
    for (int ks = 0; ks < 256; ks += 16) {
      __syncthreads();
#pragma unroll
      for (int m = 0; m < 4; ++m) {
        trbuf[(t & 15) * 68 + (t >> 4) + 16 * m] = p.La[(size_t)(i0 + (t >> 4) + 16 * m) * 256 + ks + (t & 15)];
        Ws[((t >> 6) + 4 * m) * 64 + (t & 63)] = p.T1[(size_t)(ks + (t >> 6) + 4 * m) * 64 + (t & 63)];
      }
      __syncthreads();
#pragma unroll
      for (int kk = 0; kk < 16; ++kk) {
        float4 a = *(const float4*)&trbuf[kk * 68 + tr * 4];
        float4 bv = *(const float4*)&Ws[kk * 64 + tc * 4];
        fma4x4(a, bv, acc);
      }
    }
    __syncthreads();
#pragma unroll
    for (int mi = 0; mi < 4; ++mi)
#pragma unroll
      for (int cj = 0; cj < 4; ++cj) trbuf[(tr * 4 + mi) * 68 + tc * 4 + cj] = acc[mi][cj];
    __syncthreads();
    int rr0 = t >> 4, cc4 = (t & 15) * 4;
#pragma unroll
    for (int m = 0; m < 4; ++m) {
      int rr = rr0 + 16 * m;
      float4 v = {trbuf[(cc4 + 0) * 68 + rr], trbuf[(cc4 + 1) * 68 + rr], trbuf[(cc4 + 2) * 68 + rr],
                  trbuf[(cc4 + 3) * 68 + rr]};
      *(float4*)&p.LKT[(size_t)rr * 256 + i0 + cc4] = v;
    }
    return;
  }
  const int TIa[14] = {0, 0, 0, 0, 1, 1, 1, 2, 2, 3, 0, 1, 2, 3};
  const int TJa[14] = {0, 1, 2, 3, 1, 2, 3, 2, 3, 3, 0, 0, 0, 0};
  bool isR = (u >= 10);
  int it = TIa[u], jt = TJa[u];
  int i0 = it * 64, j0 = isR ? 0 : jt * 64;
  int lane = t & 63, w = t >> 6, wr = w >> 1, wc = w & 1;
  const unsigned short* Ah = p.PTh + (size_t)b * 256 * 512;
  const unsigned short* Al = p.PTl + (size_t)b * 256 * 512;
  const unsigned short* Bh = isR ? (p.YTh + (size_t)b * 64 * 512) : Ah;
  const unsigned short* Bl = isR ? (p.YTl + (size_t)b * 64 * 512) : Al;
  int ra0 = i0 + wr * 32 + (lane & 15);
  int rb0 = j0 + wc * 32 + (lane & 15);
  int klane = (lane >> 4) * 8;
  f32x4 acc[2][2] = {};
  for (int ks = 0; ks < 512; ks += 32) {
    int kk = ks + klane;
    short8 a0h = ld8(Ah + (size_t)ra0 * 512 + kk);
    short8 a1h = ld8(Ah + (size_t)(ra0 + 16) * 512 + kk);
    short8 a0l = ld8(Al + (size_t)ra0 * 512 + kk);
    short8 a1l = ld8(Al + (size_t)(ra0 + 16) * 512 + kk);
    short8 b0h = ld8(Bh + (size_t)rb0 * 512 + kk);
    short8 b1h = ld8(Bh + (size_t)(rb0 + 16) * 512 + kk);
    short8 b0l = ld8(Bl + (size_t)rb0 * 512 + kk);
    short8 b1l = ld8(Bl + (size_t)(rb0 + 16) * 512 + kk);
    acc[0][0] = mfma3(a0h, a0l, b0h, b0l, acc[0][0]);
    acc[0][1] = mfma3(a0h, a0l, b1h, b1l, acc[0][1]);
    acc[1][0] = mfma3(a1h, a1l, b0h, b0l, acc[1][0]);
    acc[1][1] = mfma3(a1h, a1l, b1h, b1l, acc[1][1]);
  }
#pragma unroll
  for (int ti = 0; ti < 2; ++ti)
#pragma unroll
    for (int tj = 0; tj < 2; ++tj)
#pragma unroll
      for (int r = 0; r < 4; ++r)
        trbuf[(wr * 32 + ti * 16 + (lane >> 4) * 4 + r) * 68 + wc * 32 + tj * 16 + (lane & 15)] = acc[ti][tj][r];
  __syncthreads();
  int rr0 = t >> 4, cc4 = (t & 15) * 4;
  if (!isR) {
    float* Mb = p.M0 + (size_t)b * 65536;
    bool d00 = (it == 0 && jt == 0);
#pragma unroll
    for (int m = 0; m < 4; ++m) {
      int rr = rr0 + 16 * m;
      float4 v = *(float4*)&trbuf[rr * 68 + cc4];
      float4 lv = *(const float4*)&p.Lm[(size_t)(i0 + rr) * 256 + j0 + cc4];
      v.x += lv.x; v.y += lv.y; v.z += lv.z; v.w += lv.w;
      *(float4*)&Mb[(size_t)(i0 + rr) * 256 + j0 + cc4] = v;
      if (d00) *(float4*)&trbuf[rr * 68 + cc4] = v;
    }
    if (it != jt) {
#pragma unroll
      for (int m = 0; m < 4; ++m) {
        int rr = rr0 + 16 * m;
        float4 v = {trbuf[(cc4 + 0) * 68 + rr], trbuf[(cc4 + 1) * 68 + rr], trbuf[(cc4 + 2) * 68 + rr],
                    trbuf[(cc4 + 3) * 68 + rr]};
        float4 lv = *(const float4*)&p.Lm[(size_t)(j0 + rr) * 256 + i0 + cc4];
        v.x += lv.x; v.y += lv.y; v.z += lv.z; v.w += lv.w;
        *(float4*)&Mb[(size_t)(j0 + rr) * 256 + i0 + cc4] = v;
      }
    }
    if (d00) {
      __syncthreads();
      gj64<68>(trbuf, rowb, p.Dbuf + (size_t)b * 4096, t);
    }
  } else {
#pragma unroll
    for (int m = 0; m < 4; ++m) {
      int rr = rr0 + 16 * m;
      float4 v = {trbuf[(cc4 + 0) * 68 + rr], trbuf[(cc4 + 1) * 68 + rr], trbuf[(cc4 + 2) * 68 + rr],
                  trbuf[(cc4 + 3) * 68 + rr]};
      *(float4*)&p.RHST[((size_t)b * 64 + rr) * 256 + i0 + cc4] = v;
    }
  }
}

// ================= one blocked-GJ step for tile (i,j), ping-pong; kb==3 writes split-bf16 =================
__device__ void st_unit(const Params& p, int b, int u, int kb, int t, float* smem) {
  float* shA = smem;            // 64*68
  float* shB = smem + 4352;     // 64*64
  float* shD = smem + 8448;     // 64*68
  float* rowb = smem + 12800;   // 256
  int i = u >> 2, j = u & 3;
  int tr = t >> 4, tc = t & 15;
  const float* Ms = ((kb & 1) ? p.M1 : p.M0) + (size_t)b * 65536;
  float* Md = ((kb & 1) ? p.M0 : p.M1) + (size_t)b * 65536;
  const float* Din = p.Dbuf + (size_t)(kb & 1) * (B * 4096) + (size_t)b * 4096;
  float* Dout = p.Dbuf + (size_t)((kb + 1) & 1) * (B * 4096) + (size_t)b * 4096;
  bool last = (kb == 3);
  unsigned short* Yh = p.IVh + (size_t)b * 65536;
  unsigned short* Yl = p.IVl + (size_t)b * 65536;
  auto STORE = [&](int row, int col, float4 v) {
    if (last) {
      uint2 H, L;
      split4(v, H, L);
      *(uint2*)&Yh[(size_t)row * 256 + col] = H;
      *(uint2*)&Yl[(size_t)row * 256 + col] = L;
    } else {
      *(float4*)&Md[(size_t)row * 256 + col] = v;
    }
  };
  bool ik = (i == kb), jk = (j == kb);
  if (ik && jk) {
#pragma unroll
    for (int m = 0; m < 4; ++m) {
      int r = (t >> 4) + 16 * m, c4 = (t & 15) * 4;
      STORE(kb * 64 + r, kb * 64 + c4, *(const float4*)&Din[r * 64 + c4]);
    }
  } else if (ik) {  // M'[kb][j] = D * M[kb][j]
    float acc[4][4] = {};
    load_trans64(shA, 68, Din, 64, t);
    load_direct64(shB, 64, &Ms[(size_t)(kb * 64) * 256 + j * 64], 256, t);
    __syncthreads();
    gemm64<68, 64>(shA, shB, tr, tc, acc);
    __syncthreads();
#pragma unroll
    for (int mi = 0; mi < 4; ++mi) {
      float4 v = {acc[mi][0], acc[mi][1], acc[mi][2], acc[mi][3]};
      STORE(kb * 64 + tr * 4 + mi, j * 64 + tc * 4, v);
    }
  } else if (jk) {  // M'[i][kb] = -M[i][kb] * D
    float acc[4][4] = {};
    load_trans64(shA, 68, &Ms[(size_t)(i * 64) * 256 + kb * 64], 256, t);
    load_direct64(shB, 64, Din, 64, t);
    __syncthreads();
    gemm64<68, 64>(shA, shB, tr, tc, acc);
    __syncthreads();
#pragma unroll
    for (int mi = 0; mi < 4; ++mi) {
      float4 v = {-acc[mi][0], -acc[mi][1], -acc[mi][2], -acc[mi][3]};
      STORE(i * 64 + tr * 4 + mi, kb * 64 + tc * 4, v);
    }
  } else {  // update: T = D*M[kb][j]; M'[i][j] = M[i][j] - M[i][kb]*T
    float acc[4][4] = {};
    load_trans64(shA, 68, Din, 64, t);
    load_direct64(shB, 64, &Ms[(size_t)(kb * 64) * 256 + j * 64], 256, t);
    load_trans64(shD, 68, &Ms[(size_t)(i * 64) * 256 + kb * 64], 256, t);
    __syncthreads();
    gemm64<68, 64>(shA, shB, tr, tc, acc);
    __syncthreads();
#pragma unroll
    for (int mi = 0; mi < 4; ++mi) {
      float4 v = {acc[mi][0], acc[mi][1], acc[mi][2], acc[mi][3]};
      *(float4*)&shB[(tr * 4 + mi) * 64 + tc * 4] = v;  // overwrite with T
    }
    __syncthreads();
    float acc2[4][4] = {};
    gemm64<68, 64>(shD, shB, tr, tc, acc2);
    bool la = (kb < 3) && (i == kb + 1) && (j == kb + 1);
    if (la) __syncthreads();
#pragma unroll
    for (int mi = 0; mi < 4; ++mi) {
      size_t off = (size_t)(i * 64 + tr * 4 + mi) * 256 + j * 64 + tc * 4;
      float4 old = *(const float4*)&Ms[off];
      float4 v = {old.x - acc2[mi][0], old.y - acc2[mi][1], old.z - acc2[mi][2], old.w - acc2[mi][3]};
      STORE(i * 64 + tr * 4 + mi, j * 64 + tc * 4, v);
      if (la) *(float4*)&shB[(tr * 4 + mi) * 64 + tc * 4] = v;
    }
    if (la) {
      __syncthreads();
      gj64<64>(shB, rowb, Dout, t);
    }
  }
}

// ================= postK: PK = Minv @ (RHS+LK), split-bf16 out =================
__device__ void postk_unit(const Params& p, int b, int u, int t) {
  int i0 = u * 64;
  int lane = t & 63, w = t >> 6, wr = w >> 1, wc = w & 1;
  const unsigned short* Ah = p.IVh + (size_t)b * 65536;
  const unsigned short* Al = p.IVl + (size_t)b * 65536;
  int ra0 = i0 + wr * 32 + (lane & 15);
  int ob0 = wc * 32 + (lane & 15);
  int klane = (lane >> 4) * 8;
  f32x4 acc[2][2] = {};
  for (int ks = 0; ks < 256; ks += 32) {
    int kk = ks + klane;
    short8 a0h = ld8(Ah + (size_t)ra0 * 256 + kk);
    short8 a1h = ld8(Ah + (size_t)(ra0 + 16) * 256 + kk);
    short8 a0l = ld8(Al + (size_t)ra0 * 256 + kk);
    short8 a1l = ld8(Al + (size_t)(ra0 + 16) * 256 + kk);
    short8 bh[2], bl[2];
#pragma unroll
    for (int sjj = 0; sjj < 2; ++sjj) {
      int o = ob0 + sjj * 16;
      float g[8];
      float4 g0 = *(const float4*)&p.RHST[((size_t)b * 64 + o) * 256 + kk];
      float4 g1 = *(const float4*)&p.RHST[((size_t)b * 64 + o) * 256 + kk + 4];
      float4 l0 = *(const float4*)&p.LKT[(size_t)o * 256 + kk];
      float4 l1 = *(const float4*)&p.LKT[(size_t)o * 256 + kk + 4];
      g[0] = g0.x + l0.x; g[1] = g0.y + l0.y; g[2] = g0.z + l0.z; g[3] = g0.w + l0.w;
      g[4] = g1.x + l1.x; g[5] = g1.y + l1.y; g[6] = g1.z + l1.z; g[7] = g1.w + l1.w;
      cvt8(g, bh[sjj], bl[sjj]);
    }
    acc[0][0] = mfma3(a0h, a0l, bh[0], bl[0], acc[0][0]);
    acc[0][1] = mfma3(a0h, a0l, bh[1], bl[1], acc[0][1]);
    acc[1][0] = mfma3(a1h, a1l, bh[0], bl[0], acc[1][0]);
    acc[1][1] = mfma3(a1h, a1l, bh[1], bl[1], acc[1][1]);
  }
#pragma unroll
  for (int ti = 0; ti < 2; ++ti)
#pragma unroll
    for (int tj = 0; tj < 2; ++tj) {
      int ib = i0 + wr * 32 + ti * 16 + (lane >> 4) * 4;
      int o = wc * 32 + tj * 16 + (lane & 15);
      float4 v = {acc[ti][tj][0], acc[ti][tj][1], acc[ti][tj][2], acc[ti][tj][3]};
      uint2 H, L;
      split4(v, H, L);
      *(uint2*)&p.PKh[((size_t)b * 64 + o) * 256 + ib] = H;
      *(uint2*)&p.PKl[((size_t)b * 64 + o) * 256 + ib] = L;
    }
}

// ================= tail: mu + spread + sig + nll per (b, 32-row tile) =================
__device__ void tail_unit(const Params& p, int b, int qb, int t, float* smem) {
  float (*red)[4] = (float(*)[4])smem;  // [32][4]
  float* spf = smem + 128;              // [32]
  int lane = t & 63, w = t >> 6;
  int hs = w >> 1;
  int s = w & 1;
  int rows16 = qb + hs * 16;
  int qlane = rows16 + (lane & 15);
  int klane = (lane >> 4) * 8;
  const float* Pq = p.phi_q + (size_t)b * 512 * 256;
  short8 ah[8], al[8];
#pragma unroll
  for (int k8 = 0; k8 < 8; ++k8) cvt8(&Pq[(size_t)qlane * 256 + k8 * 32 + klane], ah[k8], al[k8]);

  const unsigned short* Kh = p.PKh + (size_t)b * 16384;
  const unsigned short* Kl = p.PKl + (size_t)b * 16384;
  float ssdr[4] = {0.f, 0.f, 0.f, 0.f};
#pragma unroll
  for (int oi = 0; oi < 2; ++oi) {
    int ot = s * 2 + oi;
    f32x4 acc = {};
    int orow = ot * 16 + (lane & 15);
#pragma unroll
    for (int k8 = 0; k8 < 8; ++k8) {
      short8 bh = ld8(Kh + (size_t)orow * 256 + k8 * 32 + klane);
      short8 bl = ld8(Kl + (size_t)orow * 256 + k8 * 32 + klane);
      acc = mfma3(ah[k8], al[k8], bh, bl, acc);
    }
#pragma unroll
    for (int r = 0; r < 4; ++r) {
      int qrow = rows16 + (lane >> 4) * 4 + r;
      int o = ot * 16 + (lane & 15);
      float m = acc[r];
      p.mu[((size_t)b * 512 + qrow) * 64 + o] = m;
      float d = p.y_q[((size_t)b * 512 + qrow) * 64 + o] - m;
      ssdr[r] += d * d;
    }
  }
  const unsigned short* Vh = p.IVh + (size_t)b * 65536;
  const unsigned short* Vl = p.IVl + (size_t)b * 65536;
  float rs[4] = {0.f, 0.f, 0.f, 0.f};
  for (int jt = s * 8; jt < s * 8 + 8; ++jt) {
    f32x4 acc = {};
    int jrow = jt * 16 + (lane & 15);
#pragma unroll
    for (int k8 = 0; k8 < 8; ++k8) {
      short8 bh = ld8(Vh + (size_t)jrow * 256 + k8 * 32 + klane);
      short8 bl = ld8(Vl + (size_t)jrow * 256 + k8 * 32 + klane);
      acc = mfma3(ah[k8], al[k8], bh, bl, acc);
    }
#pragma unroll
    for (int r = 0; r < 4; ++r) {
      int qrow = rows16 + (lane >> 4) * 4 + r;
      rs[r] += acc[r] * Pq[(size_t)qrow * 256 + jt * 16 + (lane & 15)];
    }
  }
#pragma unroll
  for (int off = 1; off < 16; off <<= 1)
#pragma unroll
    for (int r = 0; r < 4; ++r) {
      rs[r] += __shfl_xor(rs[r], off);
      ssdr[r] += __shfl_xor(ssdr[r], off);
    }
  if ((lane & 15) == 0) {
#pragma unroll
    for (int r = 0; r < 4; ++r) {
      int rloc = hs * 16 + (lane >> 4) * 4 + r;
      red[rloc][s] = rs[r];
      red[rloc][2 + s] = ssdr[r];
    }
  }
  __syncthreads();
  if (w == 0) {
    float val = 0.f;
    if (t < 32) {
      float sp = 1.f + red[t][0] + red[t][1];
      spf[t] = sp;
      float ssd = red[t][2] + red[t][3];
      val = (64.f * (logf(sp) + LOG_SIG_EPS) + ssd / (sp * SIG_EPS)) * (1.0f / 16384.0f);
    }
#pragma unroll
    for (int off = 32; off; off >>= 1) val += __shfl_down(val, off);
    if (t == 0) atomicAdd(p.nll, val);
  }
  __syncthreads();
  size_t base = ((size_t)b * 512 + qb) * 1024;
#pragma unroll 4
  for (int it = 0; it < 128; ++it) {
    int idx = it * 256 + t;
    int rloc = idx >> 10;
    int o = (idx >> 4) & 63;
    int p4 = idx & 15;
    float sv = spf[rloc] * SIG_EPS;
    float4 v;
    v.x = (p4 * 4 + 0 == o) ? sv : 0.f;
    v.y = (p4 * 4 + 1 == o) ? sv : 0.f;
    v.z = (p4 * 4 + 2 == o) ? sv : 0.f;
    v.w = (p4 * 4 + 3 == o) ? sv : 0.f;
    p.sig[base + idx] = v;
  }
}

// ================= cooperative mega-kernel (grid-stride; intended grid = 512 = 2/CU) =================
__global__ __launch_bounds__(256, 2) void k_all(Params p) {
  cg::grid_group grid = cg::this_grid();
  __shared__ float smem[13056];  // 52.2 KB -> 2 blocks/CU fits (104.4 of 160 KB)
  int g = blockIdx.x, t = threadIdx.x;
  int nb = gridDim.x;
  if (g == 0 && t == 0) p.nll[0] = 0.f;
  for (int w = g; w < 1300; w += nb) {
    __syncthreads();
    phase0_unit(p, w, t, smem);
  }
  __threadfence();
  grid.sync();
  for (int w = g; w < 512; w += nb) {
    __syncthreads();
    gram_unit(p, w >> 4, w & 15, t, smem);
  }
  __threadfence();
  grid.sync();
  for (int kb = 0; kb < 4; ++kb) {
    for (int w = g; w < 512; w += nb) {
      __syncthreads();
      st_unit(p, w >> 4, w & 15, kb, t, smem);
    }
    __threadfence();
    grid.sync();
  }
  for (int w = g; w < 128; w += nb) postk_unit(p, w >> 2, w & 3, t);
  __threadfence();
  grid.sync();
  for (int w = g; w < 512; w += nb) {
    __syncthreads();
    tail_unit(p, w >> 4, (w & 15) * 32, t, smem);
  }
}

// ================= fallback wrappers (plain launches) =================
__global__ __launch_bounds__(256) void k_p0(Params p) {
  __shared__ float smem[13056];
  if (blockIdx.x == 0 && threadIdx.x == 0) p.nll[0] = 0.f;
  phase0_unit(p, blockIdx.x, threadIdx.x, smem);
}
__global__ __launch_bounds__(256) void k_gramw(Params p) {
  __shared__ float smem[13056];
  gram_unit(p, blockIdx.x >> 4, blockIdx.x & 15, threadIdx.x, smem);
}
__global__ __launch_bounds__(256) void k_stw(Params p, int kb) {
  __shared__ float smem[13056];
  st_unit(p, blockIdx.x >> 4, blockIdx.x & 15, kb, threadIdx.x, smem);
}
__global__ __launch_bounds__(256) void k_postkw(Params p) {
  postk_unit(p, blockIdx.x >> 2, blockIdx.x & 3, threadIdx.x);
}
__global__ __launch_bounds__(256) void k_tailw(Params p) {
  __shared__ float smem[13056];
  tail_unit(p, blockIdx.x >> 4, (blockIdx.x & 15) * 32, threadIdx.x, smem);
}

extern "C" void kernel_launch(void* const* d_in, const int* in_sizes, int n_in, void* d_out, int out_size,
                              void* d_ws, size_t ws_size, hipStream_t stream) {
  float* ws = (float*)d_ws;
  unsigned short* u16b = (unsigned short*)(ws + WS_U16);
  float* out_mu = (float*)d_out;

  Params p;
  p.phi_s = (const float*)d_in[0];
  p.y_s = (const float*)d_in[1];
  p.phi_q = (const float*)d_in[2];
  p.y_q = (const float*)d_in[3];
  p.Km = (const float*)d_in[4];
  p.La = (const float*)d_in[5];
  p.Lm = ws + WS_L;
  p.T1 = ws + WS_T1;
  p.LKT = ws + WS_LKT;
  p.M0 = ws + WS_M0;
  p.M1 = ws + WS_M1;
  p.RHST = ws + WS_RHST;
  p.Dbuf = ws + WS_D;
  p.PTh = u16b + U_PTH;
  p.PTl = u16b + U_PTL;
  p.YTh = u16b + U_YTH;
  p.YTl = u16b + U_YTL;
  p.IVh = u16b + U_IVH;
  p.IVl = u16b + U_IVL;
  p.PKh = u16b + U_PKH;
  p.PKl = u16b + U_PKL;
  p.mu = out_mu;
  p.sig = (float4*)(out_mu + OUT_MU_ELEMS);
  p.nll = out_mu + OUT_NLL_IDX;

  int dev = 0;
  hipGetDevice(&dev);
  int coop = 0;
  hipDeviceGetAttribute(&coop, hipDeviceAttributeCooperativeLaunch, dev);
  int maxb = 0;
  hipOccupancyMaxActiveBlocksPerMultiprocessor(&maxb, (const void*)k_all, 256, 0);

  hipError_t lerr = hipErrorUnknown;
  if (coop && maxb >= 1) {
    int nblk = (maxb >= 2) ? 512 : 256;
    void* kargs[1] = {(void*)&p};
    lerr = hipLaunchCooperativeKernel((const void*)k_all, dim3(nblk, 1, 1), dim3(256, 1, 1), kargs, 0, stream);
    if (lerr != hipSuccess && nblk == 512) {
      // retry at guaranteed-resident 256 blocks before falling back
      lerr = hipLaunchCooperativeKernel((const void*)k_all, dim3(256, 1, 1), dim3(256, 1, 1), kargs, 0, stream);
    }
  }
  if (lerr != hipSuccess) {
    k_p0<<<1300, 256, 0, stream>>>(p);
    k_gramw<<<512, 256, 0, stream>>>(p);
    for (int kb = 0; kb < 4; ++kb) k_stw<<<512, 256, 0, stream>>>(p, kb);
    k_postkw<<<128, 256, 0, stream>>>(p);
    k_tailw<<<512, 256, 0, stream>>>(p);
  }
}

// Round 8
// 416.561 us; speedup vs baseline: 1.7576x; 1.7576x over previous
//
#include <hip/hip_runtime.h>
#include <math.h>

#define B 32
#define S 512
#define Q 512
#define I 256
#define O 64
#define SIG_EPS 0.1f
#define LOG_SIG_EPS (-2.3025850929940457f)

// f32 workspace offsets
#define WS_L 0
#define WS_T1 65536
#define WS_LKT 81920
#define WS_M0 98304
#define WS_M1 2195456
#define WS_RHST 4292608
#define WS_D 4816896
#define WS_U16 5079040
// u16 offsets (units of u16)
#define U_PTH 0
#define U_PTL 4194304
#define U_YTH 8388608
#define U_YTL 9437184
#define U_IVH 10485760
#define U_IVL 12582912

#define OUT_MU_ELEMS (B * Q * O)
#define OUT_SIG_ELEMS (B * Q * O * O)
#define OUT_NLL_IDX (OUT_MU_ELEMS + OUT_SIG_ELEMS)

typedef short short8 __attribute__((ext_vector_type(8)));
typedef float f32x4 __attribute__((ext_vector_type(4)));
#define MFMA16(a, b, c) __builtin_amdgcn_mfma_f32_16x16x32_bf16(a, b, c, 0, 0, 0)

struct Params {
  const float *phi_s, *y_s, *phi_q, *y_q, *Km, *La;
  float *Lm, *T1, *LKT, *M0, *M1, *RHST, *Dbuf;
  unsigned short *PTh, *PTl, *YTh, *YTl, *IVh, *IVl;
  float *mu, *nll;
  float4 *sig;
};

__device__ __forceinline__ f32x4 mfma3(short8 ah, short8 al, short8 bh, short8 bl, f32x4 c) {
  c = MFMA16(ah, bh, c);
  c = MFMA16(ah, bl, c);
  c = MFMA16(al, bh, c);
  return c;
}

__device__ __forceinline__ unsigned short f2bf(float x) {
  unsigned int u = __float_as_uint(x);
  return (unsigned short)((u + 0x7fffu + ((u >> 16) & 1u)) >> 16);
}
__device__ __forceinline__ float bf2f(unsigned short h) { return __uint_as_float(((unsigned int)h) << 16); }
__device__ __forceinline__ void split2(float x, unsigned short& h, unsigned short& l) {
  h = f2bf(x);
  l = f2bf(x - bf2f(h));
}
__device__ __forceinline__ void split4(float4 v, uint2& H, uint2& L) {
  unsigned short h0, h1, h2, h3, l0, l1, l2, l3;
  split2(v.x, h0, l0); split2(v.y, h1, l1); split2(v.z, h2, l2); split2(v.w, h3, l3);
  H.x = (unsigned)h0 | ((unsigned)h1 << 16); H.y = (unsigned)h2 | ((unsigned)h3 << 16);
  L.x = (unsigned)l0 | ((unsigned)l1 << 16); L.y = (unsigned)l2 | ((unsigned)l3 << 16);
}
__device__ __forceinline__ void cvt8(const float* p, short8& h8, short8& l8) {
  float4 a = *(const float4*)p;
  float4 b = *(const float4*)(p + 4);
  uint2 H0, L0, H1, L1;
  split4(a, H0, L0); split4(b, H1, L1);
  union { uint2 q[2]; short8 s; } uh, ul;
  uh.q[0] = H0; uh.q[1] = H1; ul.q[0] = L0; ul.q[1] = L1;
  h8 = uh.s; l8 = ul.s;
}
__device__ __forceinline__ short8 ld8(const unsigned short* p) { return *(const short8*)(const void*)p; }

__device__ __forceinline__ void fma4x4(const float4 av, const float4 bv, float acc[4][4]) {
  const float ar[4] = {av.x, av.y, av.z, av.w};
  const float br[4] = {bv.x, bv.y, bv.z, bv.w};
#pragma unroll
  for (int i = 0; i < 4; ++i)
#pragma unroll
    for (int j = 0; j < 4; ++j) acc[i][j] += ar[i] * br[j];
}

__device__ __forceinline__ void load_direct64(float* dst, int ds, const float* src, int ss, int t) {
#pragma unroll
  for (int m = 0; m < 4; ++m) {
    int r = (t >> 4) + 16 * m, c4 = (t & 15) * 4;
    *(float4*)&dst[r * ds + c4] = *(const float4*)&src[(size_t)r * ss + c4];
  }
}
__device__ __forceinline__ void load_trans64(float* dst, int ds, const float* src, int ss, int t) {
#pragma unroll
  for (int m = 0; m < 4; ++m) {
    int r = (t >> 4) + 16 * m, c4 = (t & 15) * 4;
    float4 v = *(const float4*)&src[(size_t)r * ss + c4];
    dst[(c4 + 0) * ds + r] = v.x;
    dst[(c4 + 1) * ds + r] = v.y;
    dst[(c4 + 2) * ds + r] = v.z;
    dst[(c4 + 3) * ds + r] = v.w;
  }
}
template <int SA, int SB>
__device__ __forceinline__ void gemm64(const float* At, const float* Bs, int tr, int tc, float acc[4][4]) {
#pragma unroll 8
  for (int kk = 0; kk < 64; ++kk) {
    float4 a = *(const float4*)&At[kk * SA + tr * 4];
    float4 b = *(const float4*)&Bs[kk * SB + tc * 4];
    fma4x4(a, b, acc);
  }
}

#define SC4(V) V.x *= pivinv; V.y *= pivinv; V.z *= pivinv; V.w *= pivinv
#define UP4(V, R) V.x -= g * R.x; V.y -= g * R.y; V.z -= g * R.z; V.w -= g * R.w

template <int TS>
__device__ void gj64(const float* T, float* rowbuf, float* Dout, int t) {
  int r = t >> 2, q = t & 3;
  int lane = t & 63;
  float4 A0 = *(const float4*)&T[r * TS + q * 16 + 0];
  float4 A1 = *(const float4*)&T[r * TS + q * 16 + 4];
  float4 A2 = *(const float4*)&T[r * TS + q * 16 + 8];
  float4 A3 = *(const float4*)&T[r * TS + q * 16 + 12];
#define IC(c) (((q * 16 + (c)) == r) ? 1.f : 0.f)
  float4 I0 = make_float4(IC(0), IC(1), IC(2), IC(3));
  float4 I1 = make_float4(IC(4), IC(5), IC(6), IC(7));
  float4 I2 = make_float4(IC(8), IC(9), IC(10), IC(11));
  float4 I3 = make_float4(IC(12), IC(13), IC(14), IC(15));
#undef IC
  for (int p = 0; p < 64; ++p) {
    float* RA = rowbuf + (p & 1) * 128;
    float* RI = RA + 64;
    if (r == p) {
      ((float4*)&RA[q * 16])[0] = A0; ((float4*)&RA[q * 16])[1] = A1;
      ((float4*)&RA[q * 16])[2] = A2; ((float4*)&RA[q * 16])[3] = A3;
      ((float4*)&RI[q * 16])[0] = I0; ((float4*)&RI[q * 16])[1] = I1;
      ((float4*)&RI[q * 16])[2] = I2; ((float4*)&RI[q * 16])[3] = I3;
    }
    __syncthreads();
    float pivinv = 1.0f / RA[p];
    int sidx = p & 15;
    float4 blk = (sidx < 8) ? ((sidx < 4) ? A0 : A1) : ((sidx < 12) ? A2 : A3);
    int sc = sidx & 3;
    float ap = (sc == 0) ? blk.x : (sc == 1) ? blk.y : (sc == 2) ? blk.z : blk.w;
    float f = __shfl(ap, (lane & ~3) | (p >> 4), 64);
    float4 ra0 = ((const float4*)&RA[q * 16])[0], ra1 = ((const float4*)&RA[q * 16])[1];
    float4 ra2 = ((const float4*)&RA[q * 16])[2], ra3 = ((const float4*)&RA[q * 16])[3];
    float4 ri0 = ((const float4*)&RI[q * 16])[0], ri1 = ((const float4*)&RI[q * 16])[1];
    float4 ri2 = ((const float4*)&RI[q * 16])[2], ri3 = ((const float4*)&RI[q * 16])[3];
    if (r == p) {
      SC4(A0); SC4(A1); SC4(A2); SC4(A3);
      SC4(I0); SC4(I1); SC4(I2); SC4(I3);
    } else {
      float g = f * pivinv;
      UP4(A0, ra0); UP4(A1, ra1); UP4(A2, ra2); UP4(A3, ra3);
      UP4(I0, ri0); UP4(I1, ri1); UP4(I2, ri2); UP4(I3, ri3);
    }
  }
  ((float4*)&Dout[r * 64 + q * 16])[0] = I0;
  ((float4*)&Dout[r * 64 + q * 16])[1] = I1;
  ((float4*)&Dout[r * 64 + q * 16])[2] = I2;
  ((float4*)&Dout[r * 64 + q * 16])[3] = I3;
}

// ================= k_front: cvt (blk<1280) + pre1 L/T1 (blk 1280..1299) + nll zero =================
__global__ __launch_bounds__(256) void k_front(Params p) {
  __shared__ float smem[4352];  // 17.4 KB
  int w = blockIdx.x, t = threadIdx.x;
  if (w == 0 && t == 0) p.nll[0] = 0.f;
  if (w < 1280) {
    unsigned short* Hs = (unsigned short*)smem;  // [64][68]
    unsigned short* Lo = Hs + 64 * 68;
    const float* src;
    unsigned short *dh, *dl;
    int sstride;
    if (w < 1024) {
      int b = w >> 5, r = w & 31, ic = r >> 3, sc = r & 7;
      src = p.phi_s + ((size_t)b * 512 + sc * 64) * 256 + ic * 64;
      sstride = 256;
      size_t d0 = ((size_t)b * 256 + ic * 64) * 512 + sc * 64;
      dh = p.PTh + d0; dl = p.PTl + d0;
    } else {
      int qq = w - 1024, b = qq >> 3, sc = qq & 7;
      src = p.y_s + ((size_t)b * 512 + sc * 64) * 64;
      sstride = 64;
      size_t d0 = ((size_t)b * 64) * 512 + sc * 64;
      dh = p.YTh + d0; dl = p.YTl + d0;
    }
    int c = t & 63, rb = (t >> 6) * 16;
#pragma unroll
    for (int m = 0; m < 16; ++m) {
      int s = rb + m;
      float x = src[(size_t)s * sstride + c];
      unsigned short h, l;
      split2(x, h, l);
      Hs[c * 68 + s] = h;
      Lo[c * 68 + s] = l;
    }
    __syncthreads();
    int il0 = t >> 4, c4 = (t & 15) * 4;
#pragma unroll
    for (int m = 0; m < 4; ++m) {
      int il = il0 + 16 * m;
      uint2 H, L;
      H.x = (unsigned)Hs[il * 68 + c4] | ((unsigned)Hs[il * 68 + c4 + 1] << 16);
      H.y = (unsigned)Hs[il * 68 + c4 + 2] | ((unsigned)Hs[il * 68 + c4 + 3] << 16);
      L.x = (unsigned)Lo[il * 68 + c4] | ((unsigned)Lo[il * 68 + c4 + 1] << 16);
      L.y = (unsigned)Lo[il * 68 + c4 + 2] | ((unsigned)Lo[il * 68 + c4 + 3] << 16);
      *(uint2*)&dh[(size_t)il * 512 + c4] = H;
      *(uint2*)&dl[(size_t)il * 512 + c4] = L;
    }
  } else {
    int blk2 = w - 1280;
    float* sA = smem;
    float* sB = smem + 1088;
    int tr = t >> 4, tc = t & 15;
    float acc[4][4] = {};
    if (blk2 < 16) {
      int i0 = (blk2 >> 2) * 64, j0 = (blk2 & 3) * 64;
      for (int ks = 0; ks < 256; ks += 16) {
        __syncthreads();
#pragma unroll
        for (int m = 0; m < 4; ++m) {
          int r = (t >> 4) + 16 * m, kk = t & 15;
          sA[kk * 68 + r] = p.La[(size_t)(i0 + r) * 256 + ks + kk];
          sB[kk * 68 + r] = p.La[(size_t)(j0 + r) * 256 + ks + kk];
        }
        __syncthreads();
#pragma unroll
        for (int kk = 0; kk < 16; ++kk) {
          float4 a = *(const float4*)&sA[kk * 68 + tr * 4];
          float4 bv = *(const float4*)&sB[kk * 68 + tc * 4];
          fma4x4(a, bv, acc);
        }
      }
#pragma unroll
      for (int mi = 0; mi < 4; ++mi) {
        float4 v = {acc[mi][0], acc[mi][1], acc[mi][2], acc[mi][3]};
        *(float4*)&p.Lm[(size_t)(i0 + tr * 4 + mi) * 256 + j0 + tc * 4] = v;
      }
    } else {
      int i0 = (blk2 - 16) * 64;
      for (int ks = 0; ks < 256; ks += 16) {
        __syncthreads();
#pragma unroll
        for (int m = 0; m < 4; ++m) {
          int kk = (t >> 6) + 4 * m, c = t & 63;
          sA[kk * 68 + c] = p.La[(size_t)(ks + kk) * 256 + i0 + c];
          sB[kk * 68 + c] = p.Km[(size_t)(ks + kk) * 64 + c];
        }
        __syncthreads();
#pragma unroll
        for (int kk = 0; kk < 16; ++kk) {
          float4 a = *(const float4*)&sA[kk * 68 + tr * 4];
          float4 bv = *(const float4*)&sB[kk * 68 + tc * 4];
          fma4x4(a, bv, acc);
        }
      }
#pragma unroll
      for (int mi = 0; mi < 4; ++mi) {
        float4 v = {acc[mi][0], acc[mi][1], acc[mi][2], acc[mi][3]};
        *(float4*)&p.T1[(size_t)(i0 + tr * 4 + mi) * 64 + tc * 4] = v;
      }
    }
  }
}

// ================= k_gram: u<10 sym M tiles (+mirror,+D0), u 10-13 RHST, u==14 LK (b<4) =================
__global__ __launch_bounds__(256) void k_gram(Params p) {
  __shared__ float smem[5632];  // 22.5 KB
  float* trbuf = smem;          // 64*68
  float* Ws = smem + 4352;      // 16*64
  float* rowb = smem + 5376;    // 256
  int b = blockIdx.x, u = blockIdx.y, t = threadIdx.x;
  if (u == 14) {
    if (b >= 4) return;
    int i0 = b * 64;
    int tr = t >> 4, tc = t & 15;
    float acc[4][4] = {};
    for (int ks = 0; ks < 256; ks += 16) {
      __syncthreads();
#pragma unroll
      for (int m = 0; m < 4; ++m) {
        trbuf[(t & 15) * 68 + (t >> 4) + 16 * m] = p.La[(size_t)(i0 + (t >> 4) + 16 * m) * 256 + ks + (t & 15)];
        Ws[((t >> 6) + 4 * m) * 64 + (t & 63)] = p.T1[(size_t)(ks + (t >> 6) + 4 * m) * 64 + (t & 63)];
      }
      __syncthreads();
#pragma unroll
      for (int kk = 0; kk < 16; ++kk) {
        float4 a = *(const float4*)&trbuf[kk * 68 + tr * 4];
        float4 bv = *(const float4*)&Ws[kk * 64 + tc * 4];
        fma4x4(a, bv, acc);
      }
    }
    __syncthreads();
#pragma unroll
    for (int mi = 0; mi < 4; ++mi)
#pragma unroll
      for (int cj = 0; cj < 4; ++cj) trbuf[(tr * 4 + mi) * 68 + tc * 4 + cj] = acc[mi][cj];
    __syncthreads();
    int rr0 = t >> 4, cc4 = (t & 15) * 4;
#pragma unroll
    for (int m = 0; m < 4; ++m) {
      int rr = rr0 + 16 * m;
      float4 v = {trbuf[(cc4 + 0) * 68 + rr], trbuf[(cc4 + 1) * 68 + rr], trbuf[(cc4 + 2) * 68 + rr],
                  trbuf[(cc4 + 3) * 68 + rr]};
      *(float4*)&p.LKT[(size_t)rr * 256 + i0 + cc4] = v;
    }
    return;
  }
  const int TIa[14] = {0, 0, 0, 0, 1, 1, 1, 2, 2, 3, 0, 1, 2, 3};
  const int TJa[14] = {0, 1, 2, 3, 1, 2, 3, 2, 3, 3, 0, 0, 0, 0};
  bool isR = (u >= 10);
  int it = TIa[u], jt = TJa[u];
  int i0 = it * 64, j0 = isR ? 0 : jt * 64;
  int lane = t & 63, w = t >> 6, wr = w >> 1, wc = w & 1;
  const unsigned short* Ah = p.PTh + (size_t)b * 256 * 512;
  const unsigned short* Al = p.PTl + (size_t)b * 256 * 512;
  const unsigned short* Bh = isR ? (p.YTh + (size_t)b * 64 * 512) : Ah;
  const unsigned short* Bl = isR ? (p.YTl + (size_t)b * 64 * 512) : Al;
  int ra0 = i0 + wr * 32 + (lane & 15);
  int rb0 = j0 + wc * 32 + (lane & 15);
  int klane = (lane >> 4) * 8;
  f32x4 acc[2][2] = {};
  for (int ks = 0; ks < 512; ks += 32) {
    int kk = ks + klane;
    short8 a0h = ld8(Ah + (size_t)ra0 * 512 + kk);
    short8 a1h = ld8(Ah + (size_t)(ra0 + 16) * 512 + kk);
    short8 a0l = ld8(Al + (size_t)ra0 * 512 + kk);
    short8 a1l = ld8(Al + (size_t)(ra0 + 16) * 512 + kk);
    short8 b0h = ld8(Bh + (size_t)rb0 * 512 + kk);
    short8 b1h = ld8(Bh + (size_t)(rb0 + 16) * 512 + kk);
    short8 b0l = ld8(Bl + (size_t)rb0 * 512 + kk);
    short8 b1l = ld8(Bl + (size_t)(rb0 + 16) * 512 + kk);
    acc[0][0] = mfma3(a0h, a0l, b0h, b0l, acc[0][0]);
    acc[0][1] = mfma3(a0h, a0l, b1h, b1l, acc[0][1]);
    acc[1][0] = mfma3(a1h, a1l, b0h, b0l, acc[1][0]);
    acc[1][1] = mfma3(a1h, a1l, b1h, b1l, acc[1][1]);
  }
#pragma unroll
  for (int ti = 0; ti < 2; ++ti)
#pragma unroll
    for (int tj = 0; tj < 2; ++tj)
#pragma unroll
      for (int r = 0; r < 4; ++r)
        trbuf[(wr * 32 + ti * 16 + (lane >> 4) * 4 + r) * 68 + wc * 32 + tj * 16 + (lane & 15)] = acc[ti][tj][r];
  __syncthreads();
  int rr0 = t >> 4, cc4 = (t & 15) * 4;
  if (!isR) {
    float* Mb = p.M0 + (size_t)b * 65536;
    bool d00 = (it == 0 && jt == 0);
#pragma unroll
    for (int m = 0; m < 4; ++m) {
      int rr = rr0 + 16 * m;
      float4 v = *(float4*)&trbuf[rr * 68 + cc4];
      float4 lv = *(const float4*)&p.Lm[(size_t)(i0 + rr) * 256 + j0 + cc4];
      v.x += lv.x; v.y += lv.y; v.z += lv.z; v.w += lv.w;
      *(float4*)&Mb[(size_t)(i0 + rr) * 256 + j0 + cc4] = v;
      if (d00) *(float4*)&trbuf[rr * 68 + cc4] = v;
    }
    if (it != jt) {
#pragma unroll
      for (int m = 0; m < 4; ++m) {
        int rr = rr0 + 16 * m;
        float4 v = {trbuf[(cc4 + 0) * 68 + rr], trbuf[(cc4 + 1) * 68 + rr], trbuf[(cc4 + 2) * 68 + rr],
                    trbuf[(cc4 + 3) * 68 + rr]};
        float4 lv = *(const float4*)&p.Lm[(size_t)(j0 + rr) * 256 + i0 + cc4];
        v.x += lv.x; v.y += lv.y; v.z += lv.z; v.w += lv.w;
        *(float4*)&Mb[(size_t)(j0 + rr) * 256 + i0 + cc4] = v;
      }
    }
    if (d00) {
      __syncthreads();
      gj64<68>(trbuf, rowb, p.Dbuf + (size_t)b * 4096, t);
    }
  } else {
#pragma unroll
    for (int m = 0; m < 4; ++m) {
      int rr = rr0 + 16 * m;
      float4 v = {trbuf[(cc4 + 0) * 68 + rr], trbuf[(cc4 + 1) * 68 + rr], trbuf[(cc4 + 2) * 68 + rr],
                  trbuf[(cc4 + 3) * 68 + rr]};
      *(float4*)&p.RHST[((size_t)b * 64 + rr) * 256 + i0 + cc4] = v;
    }
  }
}

// ================= k_st: blocked-GJ step (u<16); u==16 (kb0 only): RHST += LKT =================
__global__ __launch_bounds__(256) void k_st(Params p, int kb) {
  __shared__ float smem[13056];  // 52.2 KB
  float* shA = smem;             // 64*68
  float* shB = smem + 4352;      // 64*64
  float* shD = smem + 8448;      // 64*68
  float* rowb = smem + 12800;    // 256
  int b = blockIdx.x, u = blockIdx.y, t = threadIdx.x;
  if (u == 16) {  // G = RHST + LKT (in place), only launched for kb==0
    float4* R4 = (float4*)(p.RHST + (size_t)b * 16384);
    const float4* L4 = (const float4*)p.LKT;
#pragma unroll
    for (int m = 0; m < 16; ++m) {
      int idx = m * 256 + t;
      float4 a = R4[idx];
      float4 l = L4[idx];
      a.x += l.x; a.y += l.y; a.z += l.z; a.w += l.w;
      R4[idx] = a;
    }
    return;
  }
  int i = u >> 2, j = u & 3;
  int tr = t >> 4, tc = t & 15;
  const float* Ms = ((kb & 1) ? p.M1 : p.M0) + (size_t)b * 65536;
  float* Md = ((kb & 1) ? p.M0 : p.M1) + (size_t)b * 65536;
  const float* Din = p.Dbuf + (size_t)(kb & 1) * (B * 4096) + (size_t)b * 4096;
  float* Dout = p.Dbuf + (size_t)((kb + 1) & 1) * (B * 4096) + (size_t)b * 4096;
  bool last = (kb == 3);
  unsigned short* Yh = p.IVh + (size_t)b * 65536;
  unsigned short* Yl = p.IVl + (size_t)b * 65536;
  auto STORE = [&](int row, int col, float4 v) {
    if (last) {
      uint2 H, L;
      split4(v, H, L);
      *(uint2*)&Yh[(size_t)row * 256 + col] = H;
      *(uint2*)&Yl[(size_t)row * 256 + col] = L;
    } else {
      *(float4*)&Md[(size_t)row * 256 + col] = v;
    }
  };
  bool ik = (i == kb), jk = (j == kb);
  if (ik && jk) {
#pragma unroll
    for (int m = 0; m < 4; ++m) {
      int r = (t >> 4) + 16 * m, c4 = (t & 15) * 4;
      STORE(kb * 64 + r, kb * 64 + c4, *(const float4*)&Din[r * 64 + c4]);
    }
  } else if (ik) {  // M'[kb][j] = D * M[kb][j]
    float acc[4][4] = {};
    load_trans64(shA, 68, Din, 64, t);
    load_direct64(shB, 64, &Ms[(size_t)(kb * 64) * 256 + j * 64], 256, t);
    __syncthreads();
    gemm64<68, 64>(shA, shB, tr, tc, acc);
    __syncthreads();
#pragma unroll
    for (int mi = 0; mi < 4; ++mi) {
      float4 v = {acc[mi][0], acc[mi][1], acc[mi][2], acc[mi][3]};
      STORE(kb * 64 + tr * 4 + mi, j * 64 + tc * 4, v);
    }
  } else if (jk) {  // M'[i][kb] = -M[i][kb] * D
    float acc[4][4] = {};
    load_trans64(shA, 68, &Ms[(size_t)(i * 64) * 256 + kb * 64], 256, t);
    load_direct64(shB, 64, Din, 64, t);
    __syncthreads();
    gemm64<68, 64>(shA, shB, tr, tc, acc);
    __syncthreads();
#pragma unroll
    for (int mi = 0; mi < 4; ++mi) {
      float4 v = {-acc[mi][0], -acc[mi][1], -acc[mi][2], -acc[mi][3]};
      STORE(i * 64 + tr * 4 + mi, kb * 64 + tc * 4, v);
    }
  } else {  // update: T = D*M[kb][j]; M'[i][j] = M[i][j] - M[i][kb]*T
    float acc[4][4] = {};
    load_trans64(shA, 68, Din, 64, t);
    load_direct64(shB, 64, &Ms[(size_t)(kb * 64) * 256 + j * 64], 256, t);
    load_trans64(shD, 68, &Ms[(size_t)(i * 64) * 256 + kb * 64], 256, t);
    __syncthreads();
    gemm64<68, 64>(shA, shB, tr, tc, acc);
    __syncthreads();
#pragma unroll
    for (int mi = 0; mi < 4; ++mi) {
      float4 v = {acc[mi][0], acc[mi][1], acc[mi][2], acc[mi][3]};
      *(float4*)&shB[(tr * 4 + mi) * 64 + tc * 4] = v;  // overwrite with T
    }
    __syncthreads();
    float acc2[4][4] = {};
    gemm64<68, 64>(shD, shB, tr, tc, acc2);
    bool la = (kb < 3) && (i == kb + 1) && (j == kb + 1);
    if (la) __syncthreads();
#pragma unroll
    for (int mi = 0; mi < 4; ++mi) {
      size_t off = (size_t)(i * 64 + tr * 4 + mi) * 256 + j * 64 + tc * 4;
      float4 old = *(const float4*)&Ms[off];
      float4 v = {old.x - acc2[mi][0], old.y - acc2[mi][1], old.z - acc2[mi][2], old.w - acc2[mi][3]};
      STORE(i * 64 + tr * 4 + mi, j * 64 + tc * 4, v);
      if (la) *(float4*)&shB[(tr * 4 + mi) * 64 + tc * 4] = v;
    }
    if (la) {
      __syncthreads();
      gj64<64>(shB, rowb, Dout, t);
    }
  }
}

// ================= k_tail: X = phi_q@Minv (MFMA) -> spread + mu = X@G + sig + nll =================
__global__ __launch_bounds__(256) void k_tail(Params p) {
  __shared__ float Xlds[32 * 264];  // 33.8 KB
  __shared__ float red[32][2];
  __shared__ float spf[32];
  __shared__ float ssdl[32];
  int b = blockIdx.x, qb = blockIdx.y * 32, t = threadIdx.x;
  int lane = t & 63, w = t >> 6;
  int hs = w >> 1;  // which 16-row strip
  int s = w & 1;    // jt-half split
  int rows16 = qb + hs * 16;
  int qlane = rows16 + (lane & 15);
  int klane = (lane >> 4) * 8;
  const float* Pq = p.phi_q + (size_t)b * 512 * 256;
  short8 ah[8], al[8];
#pragma unroll
  for (int k8 = 0; k8 < 8; ++k8) cvt8(&Pq[(size_t)qlane * 256 + k8 * 32 + klane], ah[k8], al[k8]);

  // Phase A: X = phi_q @ Minv (this block's 32 rows), store to LDS + spread partials
  const unsigned short* Vh = p.IVh + (size_t)b * 65536;
  const unsigned short* Vl = p.IVl + (size_t)b * 65536;
  float rs[4] = {0.f, 0.f, 0.f, 0.f};
  for (int jt = s * 8; jt < s * 8 + 8; ++jt) {
    f32x4 acc = {};
    int jrow = jt * 16 + (lane & 15);
#pragma unroll
    for (int k8 = 0; k8 < 8; ++k8) {
      short8 bh = ld8(Vh + (size_t)jrow * 256 + k8 * 32 + klane);
      short8 bl = ld8(Vl + (size_t)jrow * 256 + k8 * 32 + klane);
      acc = mfma3(ah[k8], al[k8], bh, bl, acc);
    }
#pragma unroll
    for (int r = 0; r < 4; ++r) {
      int xq = hs * 16 + (lane >> 4) * 4 + r;
      int xi = jt * 16 + (lane & 15);
      Xlds[xq * 264 + xi] = acc[r];
      rs[r] += acc[r] * Pq[(size_t)(rows16 + (lane >> 4) * 4 + r) * 256 + xi];
    }
  }
#pragma unroll
  for (int off = 1; off < 16; off <<= 1)
#pragma unroll
    for (int r = 0; r < 4; ++r) rs[r] += __shfl_xor(rs[r], off);
  if ((lane & 15) == 0) {
#pragma unroll
    for (int r = 0; r < 4; ++r) red[hs * 16 + (lane >> 4) * 4 + r][s] = rs[r];
  }
  __syncthreads();

  // Phase B: spread
  if (t < 32) spf[t] = 1.f + red[t][0] + red[t][1];

  // Phase C: mu = X @ G^T (G = RHST + LKT, [64 o][256 i]); ssd inline
  {
    int q = t >> 3, o0 = (t & 7) * 8;
    const float* Gr = p.RHST + (size_t)b * 16384;
    float accv[8] = {};
#pragma unroll 2
    for (int i = 0; i < 256; i += 4) {
      float4 xv = *(const float4*)&Xlds[q * 264 + i];
#pragma unroll
      for (int oo = 0; oo < 8; ++oo) {
        float4 gv = *(const float4*)&Gr[(size_t)(o0 + oo) * 256 + i];
        accv[oo] += xv.x * gv.x + xv.y * gv.y + xv.z * gv.z + xv.w * gv.w;
      }
    }
    size_t qg = (size_t)b * 512 + qb + q;
    float4 m0 = {accv[0], accv[1], accv[2], accv[3]};
    float4 m1 = {accv[4], accv[5], accv[6], accv[7]};
    *(float4*)&p.mu[qg * 64 + o0] = m0;
    *(float4*)&p.mu[qg * 64 + o0 + 4] = m1;
    float4 y0 = *(const float4*)&p.y_q[qg * 64 + o0];
    float4 y1 = *(const float4*)&p.y_q[qg * 64 + o0 + 4];
    float d;
    float ssd8 = 0.f;
    d = y0.x - m0.x; ssd8 += d * d;
    d = y0.y - m0.y; ssd8 += d * d;
    d = y0.z - m0.z; ssd8 += d * d;
    d = y0.w - m0.w; ssd8 += d * d;
    d = y1.x - m1.x; ssd8 += d * d;
    d = y1.y - m1.y; ssd8 += d * d;
    d = y1.z - m1.z; ssd8 += d * d;
    d = y1.w - m1.w; ssd8 += d * d;
    ssd8 += __shfl_xor(ssd8, 1);
    ssd8 += __shfl_xor(ssd8, 2);
    ssd8 += __shfl_xor(ssd8, 4);
    if ((t & 7) == 0) ssdl[q] = ssd8;
  }
  __syncthreads();

  // Phase D: nll partial (wave 0)
  if (w == 0) {
    float val = 0.f;
    if (t < 32) {
      float sp = spf[t];
      val = (64.f * (logf(sp) + LOG_SIG_EPS) + ssdl[t] / (sp * SIG_EPS)) * (1.0f / 16384.0f);
    }
#pragma unroll
    for (int off = 32; off; off >>= 1) val += __shfl_down(val, off);
    if (t == 0) atomicAdd(p.nll, val);
  }

  // Phase E: sig fill (32 rows x 1024 float4)
  size_t base = ((size_t)b * 512 + qb) * 1024;
#pragma unroll 4
  for (int it = 0; it < 128; ++it) {
    int idx = it * 256 + t;
    int rloc = idx >> 10;
    int o = (idx >> 4) & 63;
    int p4 = idx & 15;
    float sv = spf[rloc] * SIG_EPS;
    float4 v;
    v.x = (p4 * 4 + 0 == o) ? sv : 0.f;
    v.y = (p4 * 4 + 1 == o) ? sv : 0.f;
    v.z = (p4 * 4 + 2 == o) ? sv : 0.f;
    v.w = (p4 * 4 + 3 == o) ? sv : 0.f;
    p.sig[base + idx] = v;
  }
}

extern "C" void kernel_launch(void* const* d_in, const int* in_sizes, int n_in, void* d_out, int out_size,
                              void* d_ws, size_t ws_size, hipStream_t stream) {
  float* ws = (float*)d_ws;
  unsigned short* u16b = (unsigned short*)(ws + WS_U16);
  float* out_mu = (float*)d_out;

  Params p;
  p.phi_s = (const float*)d_in[0];
  p.y_s = (const float*)d_in[1];
  p.phi_q = (const float*)d_in[2];
  p.y_q = (const float*)d_in[3];
  p.Km = (const float*)d_in[4];
  p.La = (const float*)d_in[5];
  p.Lm = ws + WS_L;
  p.T1 = ws + WS_T1;
  p.LKT = ws + WS_LKT;
  p.M0 = ws + WS_M0;
  p.M1 = ws + WS_M1;
  p.RHST = ws + WS_RHST;
  p.Dbuf = ws + WS_D;
  p.PTh = u16b + U_PTH;
  p.PTl = u16b + U_PTL;
  p.YTh = u16b + U_YTH;
  p.YTl = u16b + U_YTL;
  p.IVh = u16b + U_IVH;
  p.IVl = u16b + U_IVL;
  p.mu = out_mu;
  p.sig = (float4*)(out_mu + OUT_MU_ELEMS);
  p.nll = out_mu + OUT_NLL_IDX;

  k_front<<<1300, 256, 0, stream>>>(p);
  k_gram<<<dim3(B, 15), 256, 0, stream>>>(p);
  k_st<<<dim3(B, 17), 256, 0, stream>>>(p, 0);
  k_st<<<dim3(B, 16), 256, 0, stream>>>(p, 1);
  k_st<<<dim3(B, 16), 256, 0, stream>>>(p, 2);
  k_st<<<dim3(B, 16), 256, 0, stream>>>(p, 3);
  k_tail<<<dim3(B, 16), 256, 0, stream>>>(p);
}

// Round 9
// 309.391 us; speedup vs baseline: 2.3664x; 1.3464x over previous
//
#include <hip/hip_runtime.h>
#include <math.h>

#define B 32
#define S 512
#define Q 512
#define I 256
#define O 64
#define SIG_EPS 0.1f
#define LOG_SIG_EPS (-2.3025850929940457f)

// f32 workspace offsets
#define WS_L 0
#define WS_T1 65536
#define WS_LKT 81920
#define WS_M0 98304
#define WS_M1 2195456
#define WS_RHST 4292608
#define WS_D 4816896
#define WS_SPF 5079040
#define WS_U16 5095488
// u16 offsets (units of u16)
#define U_PTH 0
#define U_PTL 4194304
#define U_YTH 8388608
#define U_YTL 9437184
#define U_IVH 10485760
#define U_IVL 12582912

#define OUT_MU_ELEMS (B * Q * O)
#define OUT_SIG_ELEMS (B * Q * O * O)
#define OUT_NLL_IDX (OUT_MU_ELEMS + OUT_SIG_ELEMS)

typedef short short8 __attribute__((ext_vector_type(8)));
typedef float f32x4 __attribute__((ext_vector_type(4)));
#define MFMA16(a, b, c) __builtin_amdgcn_mfma_f32_16x16x32_bf16(a, b, c, 0, 0, 0)

struct Params {
  const float *phi_s, *y_s, *phi_q, *y_q, *Km, *La;
  float *Lm, *T1, *LKT, *M0, *M1, *RHST, *Dbuf, *spws;
  unsigned short *PTh, *PTl, *YTh, *YTl, *IVh, *IVl;
  float *mu, *nll;
  float4 *sig;
};

__device__ __forceinline__ f32x4 mfma3(short8 ah, short8 al, short8 bh, short8 bl, f32x4 c) {
  c = MFMA16(ah, bh, c);
  c = MFMA16(ah, bl, c);
  c = MFMA16(al, bh, c);
  return c;
}

__device__ __forceinline__ unsigned short f2bf(float x) {
  unsigned int u = __float_as_uint(x);
  return (unsigned short)((u + 0x7fffu + ((u >> 16) & 1u)) >> 16);
}
__device__ __forceinline__ float bf2f(unsigned short h) { return __uint_as_float(((unsigned int)h) << 16); }
__device__ __forceinline__ void split2(float x, unsigned short& h, unsigned short& l) {
  h = f2bf(x);
  l = f2bf(x - bf2f(h));
}
__device__ __forceinline__ void split4(float4 v, uint2& H, uint2& L) {
  unsigned short h0, h1, h2, h3, l0, l1, l2, l3;
  split2(v.x, h0, l0); split2(v.y, h1, l1); split2(v.z, h2, l2); split2(v.w, h3, l3);
  H.x = (unsigned)h0 | ((unsigned)h1 << 16); H.y = (unsigned)h2 | ((unsigned)h3 << 16);
  L.x = (unsigned)l0 | ((unsigned)l1 << 16); L.y = (unsigned)l2 | ((unsigned)l3 << 16);
}
__device__ __forceinline__ void cvt8(const float* p, short8& h8, short8& l8) {
  float4 a = *(const float4*)p;
  float4 b = *(const float4*)(p + 4);
  uint2 H0, L0, H1, L1;
  split4(a, H0, L0); split4(b, H1, L1);
  union { uint2 q[2]; short8 s; } uh, ul;
  uh.q[0] = H0; uh.q[1] = H1; ul.q[0] = L0; ul.q[1] = L1;
  h8 = uh.s; l8 = ul.s;
}
__device__ __forceinline__ short8 ld8(const unsigned short* p) { return *(const short8*)(const void*)p; }

__device__ __forceinline__ void fma4x4(const float4 av, const float4 bv, float acc[4][4]) {
  const float ar[4] = {av.x, av.y, av.z, av.w};
  const float br[4] = {bv.x, bv.y, bv.z, bv.w};
#pragma unroll
  for (int i = 0; i < 4; ++i)
#pragma unroll
    for (int j = 0; j < 4; ++j) acc[i][j] += ar[i] * br[j];
}

__device__ __forceinline__ void load_direct64(float* dst, int ds, const float* src, int ss, int t) {
#pragma unroll
  for (int m = 0; m < 4; ++m) {
    int r = (t >> 4) + 16 * m, c4 = (t & 15) * 4;
    *(float4*)&dst[r * ds + c4] = *(const float4*)&src[(size_t)r * ss + c4];
  }
}
__device__ __forceinline__ void load_trans64(float* dst, int ds, const float* src, int ss, int t) {
#pragma unroll
  for (int m = 0; m < 4; ++m) {
    int r = (t >> 4) + 16 * m, c4 = (t & 15) * 4;
    float4 v = *(const float4*)&src[(size_t)r * ss + c4];
    dst[(c4 + 0) * ds + r] = v.x;
    dst[(c4 + 1) * ds + r] = v.y;
    dst[(c4 + 2) * ds + r] = v.z;
    dst[(c4 + 3) * ds + r] = v.w;
  }
}
template <int SA, int SB>
__device__ __forceinline__ void gemm64(const float* At, const float* Bs, int tr, int tc, float acc[4][4]) {
#pragma unroll 8
  for (int kk = 0; kk < 64; ++kk) {
    float4 a = *(const float4*)&At[kk * SA + tr * 4];
    float4 b = *(const float4*)&Bs[kk * SB + tc * 4];
    fma4x4(a, b, acc);
  }
}

#define SC4(V) V.x *= pivinv; V.y *= pivinv; V.z *= pivinv; V.w *= pivinv
#define UP4(V, R) V.x -= g * R.x; V.y -= g * R.y; V.z -= g * R.z; V.w -= g * R.w

template <int TS>
__device__ void gj64(const float* T, float* rowbuf, float* Dout, int t) {
  int r = t >> 2, q = t & 3;
  int lane = t & 63;
  float4 A0 = *(const float4*)&T[r * TS + q * 16 + 0];
  float4 A1 = *(const float4*)&T[r * TS + q * 16 + 4];
  float4 A2 = *(const float4*)&T[r * TS + q * 16 + 8];
  float4 A3 = *(const float4*)&T[r * TS + q * 16 + 12];
#define IC(c) (((q * 16 + (c)) == r) ? 1.f : 0.f)
  float4 I0 = make_float4(IC(0), IC(1), IC(2), IC(3));
  float4 I1 = make_float4(IC(4), IC(5), IC(6), IC(7));
  float4 I2 = make_float4(IC(8), IC(9), IC(10), IC(11));
  float4 I3 = make_float4(IC(12), IC(13), IC(14), IC(15));
#undef IC
  for (int p = 0; p < 64; ++p) {
    float* RA = rowbuf + (p & 1) * 128;
    float* RI = RA + 64;
    if (r == p) {
      ((float4*)&RA[q * 16])[0] = A0; ((float4*)&RA[q * 16])[1] = A1;
      ((float4*)&RA[q * 16])[2] = A2; ((float4*)&RA[q * 16])[3] = A3;
      ((float4*)&RI[q * 16])[0] = I0; ((float4*)&RI[q * 16])[1] = I1;
      ((float4*)&RI[q * 16])[2] = I2; ((float4*)&RI[q * 16])[3] = I3;
    }
    __syncthreads();
    float pivinv = 1.0f / RA[p];
    int sidx = p & 15;
    float4 blk = (sidx < 8) ? ((sidx < 4) ? A0 : A1) : ((sidx < 12) ? A2 : A3);
    int sc = sidx & 3;
    float ap = (sc == 0) ? blk.x : (sc == 1) ? blk.y : (sc == 2) ? blk.z : blk.w;
    float f = __shfl(ap, (lane & ~3) | (p >> 4), 64);
    float4 ra0 = ((const float4*)&RA[q * 16])[0], ra1 = ((const float4*)&RA[q * 16])[1];
    float4 ra2 = ((const float4*)&RA[q * 16])[2], ra3 = ((const float4*)&RA[q * 16])[3];
    float4 ri0 = ((const float4*)&RI[q * 16])[0], ri1 = ((const float4*)&RI[q * 16])[1];
    float4 ri2 = ((const float4*)&RI[q * 16])[2], ri3 = ((const float4*)&RI[q * 16])[3];
    if (r == p) {
      SC4(A0); SC4(A1); SC4(A2); SC4(A3);
      SC4(I0); SC4(I1); SC4(I2); SC4(I3);
    } else {
      float g = f * pivinv;
      UP4(A0, ra0); UP4(A1, ra1); UP4(A2, ra2); UP4(A3, ra3);
      UP4(I0, ri0); UP4(I1, ri1); UP4(I2, ri2); UP4(I3, ri3);
    }
  }
  ((float4*)&Dout[r * 64 + q * 16])[0] = I0;
  ((float4*)&Dout[r * 64 + q * 16])[1] = I1;
  ((float4*)&Dout[r * 64 + q * 16])[2] = I2;
  ((float4*)&Dout[r * 64 + q * 16])[3] = I3;
}

// ================= k_front: cvt (blk<1280) + pre1 L/T1 (blk 1280..1299) + nll zero =================
__global__ __launch_bounds__(256) void k_front(Params p) {
  __shared__ float smem[4352];
  int w = blockIdx.x, t = threadIdx.x;
  if (w == 0 && t == 0) p.nll[0] = 0.f;
  if (w < 1280) {
    unsigned short* Hs = (unsigned short*)smem;
    unsigned short* Lo = Hs + 64 * 68;
    const float* src;
    unsigned short *dh, *dl;
    int sstride;
    if (w < 1024) {
      int b = w >> 5, r = w & 31, ic = r >> 3, sc = r & 7;
      src = p.phi_s + ((size_t)b * 512 + sc * 64) * 256 + ic * 64;
      sstride = 256;
      size_t d0 = ((size_t)b * 256 + ic * 64) * 512 + sc * 64;
      dh = p.PTh + d0; dl = p.PTl + d0;
    } else {
      int qq = w - 1024, b = qq >> 3, sc = qq & 7;
      src = p.y_s + ((size_t)b * 512 + sc * 64) * 64;
      sstride = 64;
      size_t d0 = ((size_t)b * 64) * 512 + sc * 64;
      dh = p.YTh + d0; dl = p.YTl + d0;
    }
    int c = t & 63, rb = (t >> 6) * 16;
#pragma unroll
    for (int m = 0; m < 16; ++m) {
      int s = rb + m;
      float x = src[(size_t)s * sstride + c];
      unsigned short h, l;
      split2(x, h, l);
      Hs[c * 68 + s] = h;
      Lo[c * 68 + s] = l;
    }
    __syncthreads();
    int il0 = t >> 4, c4 = (t & 15) * 4;
#pragma unroll
    for (int m = 0; m < 4; ++m) {
      int il = il0 + 16 * m;
      uint2 H, L;
      H.x = (unsigned)Hs[il * 68 + c4] | ((unsigned)Hs[il * 68 + c4 + 1] << 16);
      H.y = (unsigned)Hs[il * 68 + c4 + 2] | ((unsigned)Hs[il * 68 + c4 + 3] << 16);
      L.x = (unsigned)Lo[il * 68 + c4] | ((unsigned)Lo[il * 68 + c4 + 1] << 16);
      L.y = (unsigned)Lo[il * 68 + c4 + 2] | ((unsigned)Lo[il * 68 + c4 + 3] << 16);
      *(uint2*)&dh[(size_t)il * 512 + c4] = H;
      *(uint2*)&dl[(size_t)il * 512 + c4] = L;
    }
  } else {
    int blk2 = w - 1280;
    float* sA = smem;
    float* sB = smem + 1088;
    int tr = t >> 4, tc = t & 15;
    float acc[4][4] = {};
    if (blk2 < 16) {
      int i0 = (blk2 >> 2) * 64, j0 = (blk2 & 3) * 64;
      for (int ks = 0; ks < 256; ks += 16) {
        __syncthreads();
#pragma unroll
        for (int m = 0; m < 4; ++m) {
          int r = (t >> 4) + 16 * m, kk = t & 15;
          sA[kk * 68 + r] = p.La[(size_t)(i0 + r) * 256 + ks + kk];
          sB[kk * 68 + r] = p.La[(size_t)(j0 + r) * 256 + ks + kk];
        }
        __syncthreads();
#pragma unroll
        for (int kk = 0; kk < 16; ++kk) {
          float4 a = *(const float4*)&sA[kk * 68 + tr * 4];
          float4 bv = *(const float4*)&sB[kk * 68 + tc * 4];
          fma4x4(a, bv, acc);
        }
      }
#pragma unroll
      for (int mi = 0; mi < 4; ++mi) {
        float4 v = {acc[mi][0], acc[mi][1], acc[mi][2], acc[mi][3]};
        *(float4*)&p.Lm[(size_t)(i0 + tr * 4 + mi) * 256 + j0 + tc * 4] = v;
      }
    } else {
      int i0 = (blk2 - 16) * 64;
      for (int ks = 0; ks < 256; ks += 16) {
        __syncthreads();
#pragma unroll
        for (int m = 0; m < 4; ++m) {
          int kk = (t >> 6) + 4 * m, c = t & 63;
          sA[kk * 68 + c] = p.La[(size_t)(ks + kk) * 256 + i0 + c];
          sB[kk * 68 + c] = p.Km[(size_t)(ks + kk) * 64 + c];
        }
        __syncthreads();
#pragma unroll
        for (int kk = 0; kk < 16; ++kk) {
          float4 a = *(const float4*)&sA[kk * 68 + tr * 4];
          float4 bv = *(const float4*)&sB[kk * 68 + tc * 4];
          fma4x4(a, bv, acc);
        }
      }
#pragma unroll
      for (int mi = 0; mi < 4; ++mi) {
        float4 v = {acc[mi][0], acc[mi][1], acc[mi][2], acc[mi][3]};
        *(float4*)&p.T1[(size_t)(i0 + tr * 4 + mi) * 64 + tc * 4] = v;
      }
    }
  }
}

// ================= k_gram: u<10 sym M tiles (+mirror,+D0), u 10-13 RHST, u==14 LK (b<4) =================
__global__ __launch_bounds__(256) void k_gram(Params p) {
  __shared__ float smem[5632];
  float* trbuf = smem;
  float* Ws = smem + 4352;
  float* rowb = smem + 5376;
  int b = blockIdx.x, u = blockIdx.y, t = threadIdx.x;
  if (u == 14) {
    if (b >= 4) return;
    int i0 = b * 64;
    int tr = t >> 4, tc = t & 15;
    float acc[4][4] = {};
    for (int ks = 0; ks < 256; ks += 16) {
      __syncthreads();
#pragma unroll
      for (int m = 0; m < 4; ++m) {
        trbuf[(t & 15) * 68 + (t >> 4) + 16 * m] = p.La[(size_t)(i0 + (t >> 4) + 16 * m) * 256 + ks + (t & 15)];
        Ws[((t >> 6) + 4 * m) * 64 + (t & 63)] = p.T1[(size_t)(ks + (t >> 6) + 4 * m) * 64 + (t & 63)];
      }
      __syncthreads();
#pragma unroll
      for (int kk = 0; kk < 16; ++kk) {
        float4 a = *(const float4*)&trbuf[kk * 68 + tr * 4];
        float4 bv = *(const float4*)&Ws[kk * 64 + tc * 4];
        fma4x4(a, bv, acc);
      }
    }
    __syncthreads();
#pragma unroll
    for (int mi = 0; mi < 4; ++mi)
#pragma unroll
      for (int cj = 0; cj < 4; ++cj) trbuf[(tr * 4 + mi) * 68 + tc * 4 + cj] = acc[mi][cj];
    __syncthreads();
    int rr0 = t >> 4, cc4 = (t & 15) * 4;
#pragma unroll
    for (int m = 0; m < 4; ++m) {
      int rr = rr0 + 16 * m;
      float4 v = {trbuf[(cc4 + 0) * 68 + rr], trbuf[(cc4 + 1) * 68 + rr], trbuf[(cc4 + 2) * 68 + rr],
                  trbuf[(cc4 + 3) * 68 + rr]};
      *(float4*)&p.LKT[(size_t)rr * 256 + i0 + cc4] = v;
    }
    return;
  }
  const int TIa[14] = {0, 0, 0, 0, 1, 1, 1, 2, 2, 3, 0, 1, 2, 3};
  const int TJa[14] = {0, 1, 2, 3, 1, 2, 3, 2, 3, 3, 0, 0, 0, 0};
  bool isR = (u >= 10);
  int it = TIa[u], jt = TJa[u];
  int i0 = it * 64, j0 = isR ? 0 : jt * 64;
  int lane = t & 63, w = t >> 6, wr = w >> 1, wc = w & 1;
  const unsigned short* Ah = p.PTh + (size_t)b * 256 * 512;
  const unsigned short* Al = p.PTl + (size_t)b * 256 * 512;
  const unsigned short* Bh = isR ? (p.YTh + (size_t)b * 64 * 512) : Ah;
  const unsigned short* Bl = isR ? (p.YTl + (size_t)b * 64 * 512) : Al;
  int ra0 = i0 + wr * 32 + (lane & 15);
  int rb0 = j0 + wc * 32 + (lane & 15);
  int klane = (lane >> 4) * 8;
  f32x4 acc[2][2] = {};
  for (int ks = 0; ks < 512; ks += 32) {
    int kk = ks + klane;
    short8 a0h = ld8(Ah + (size_t)ra0 * 512 + kk);
    short8 a1h = ld8(Ah + (size_t)(ra0 + 16) * 512 + kk);
    short8 a0l = ld8(Al + (size_t)ra0 * 512 + kk);
    short8 a1l = ld8(Al + (size_t)(ra0 + 16) * 512 + kk);
    short8 b0h = ld8(Bh + (size_t)rb0 * 512 + kk);
    short8 b1h = ld8(Bh + (size_t)(rb0 + 16) * 512 + kk);
    short8 b0l = ld8(Bl + (size_t)rb0 * 512 + kk);
    short8 b1l = ld8(Bl + (size_t)(rb0 + 16) * 512 + kk);
    acc[0][0] = mfma3(a0h, a0l, b0h, b0l, acc[0][0]);
    acc[0][1] = mfma3(a0h, a0l, b1h, b1l, acc[0][1]);
    acc[1][0] = mfma3(a1h, a1l, b0h, b0l, acc[1][0]);
    acc[1][1] = mfma3(a1h, a1l, b1h, b1l, acc[1][1]);
  }
#pragma unroll
  for (int ti = 0; ti < 2; ++ti)
#pragma unroll
    for (int tj = 0; tj < 2; ++tj)
#pragma unroll
      for (int r = 0; r < 4; ++r)
        trbuf[(wr * 32 + ti * 16 + (lane >> 4) * 4 + r) * 68 + wc * 32 + tj * 16 + (lane & 15)] = acc[ti][tj][r];
  __syncthreads();
  int rr0 = t >> 4, cc4 = (t & 15) * 4;
  if (!isR) {
    float* Mb = p.M0 + (size_t)b * 65536;
    bool d00 = (it == 0 && jt == 0);
#pragma unroll
    for (int m = 0; m < 4; ++m) {
      int rr = rr0 + 16 * m;
      float4 v = *(float4*)&trbuf[rr * 68 + cc4];
      float4 lv = *(const float4*)&p.Lm[(size_t)(i0 + rr) * 256 + j0 + cc4];
      v.x += lv.x; v.y += lv.y; v.z += lv.z; v.w += lv.w;
      *(float4*)&Mb[(size_t)(i0 + rr) * 256 + j0 + cc4] = v;
      if (d00) *(float4*)&trbuf[rr * 68 + cc4] = v;
    }
    if (it != jt) {
#pragma unroll
      for (int m = 0; m < 4; ++m) {
        int rr = rr0 + 16 * m;
        float4 v = {trbuf[(cc4 + 0) * 68 + rr], trbuf[(cc4 + 1) * 68 + rr], trbuf[(cc4 + 2) * 68 + rr],
                    trbuf[(cc4 + 3) * 68 + rr]};
        float4 lv = *(const float4*)&p.Lm[(size_t)(j0 + rr) * 256 + i0 + cc4];
        v.x += lv.x; v.y += lv.y; v.z += lv.z; v.w += lv.w;
        *(float4*)&Mb[(size_t)(j0 + rr) * 256 + i0 + cc4] = v;
      }
    }
    if (d00) {
      __syncthreads();
      gj64<68>(trbuf, rowb, p.Dbuf + (size_t)b * 4096, t);
    }
  } else {
#pragma unroll
    for (int m = 0; m < 4; ++m) {
      int rr = rr0 + 16 * m;
      float4 v = {trbuf[(cc4 + 0) * 68 + rr], trbuf[(cc4 + 1) * 68 + rr], trbuf[(cc4 + 2) * 68 + rr],
                  trbuf[(cc4 + 3) * 68 + rr]};
      *(float4*)&p.RHST[((size_t)b * 64 + rr) * 256 + i0 + cc4] = v;
    }
  }
}

// ================= k_st: blocked-GJ step (u<16); u==16 (kb0 only): RHST += LKT =================
__global__ __launch_bounds__(256) void k_st(Params p, int kb) {
  __shared__ float smem[13056];
  float* shA = smem;
  float* shB = smem + 4352;
  float* shD = smem + 8448;
  float* rowb = smem + 12800;
  int b = blockIdx.x, u = blockIdx.y, t = threadIdx.x;
  if (u == 16) {
    float4* R4 = (float4*)(p.RHST + (size_t)b * 16384);
    const float4* L4 = (const float4*)p.LKT;
#pragma unroll
    for (int m = 0; m < 16; ++m) {
      int idx = m * 256 + t;
      float4 a = R4[idx];
      float4 l = L4[idx];
      a.x += l.x; a.y += l.y; a.z += l.z; a.w += l.w;
      R4[idx] = a;
    }
    return;
  }
  int i = u >> 2, j = u & 3;
  int tr = t >> 4, tc = t & 15;
  const float* Ms = ((kb & 1) ? p.M1 : p.M0) + (size_t)b * 65536;
  float* Md = ((kb & 1) ? p.M0 : p.M1) + (size_t)b * 65536;
  const float* Din = p.Dbuf + (size_t)(kb & 1) * (B * 4096) + (size_t)b * 4096;
  float* Dout = p.Dbuf + (size_t)((kb + 1) & 1) * (B * 4096) + (size_t)b * 4096;
  bool last = (kb == 3);
  unsigned short* Yh = p.IVh + (size_t)b * 65536;
  unsigned short* Yl = p.IVl + (size_t)b * 65536;
  auto STORE = [&](int row, int col, float4 v) {
    if (last) {
      uint2 H, L;
      split4(v, H, L);
      *(uint2*)&Yh[(size_t)row * 256 + col] = H;
      *(uint2*)&Yl[(size_t)row * 256 + col] = L;
    } else {
      *(float4*)&Md[(size_t)row * 256 + col] = v;
    }
  };
  bool ik = (i == kb), jk = (j == kb);
  if (ik && jk) {
#pragma unroll
    for (int m = 0; m < 4; ++m) {
      int r = (t >> 4) + 16 * m, c4 = (t & 15) * 4;
      STORE(kb * 64 + r, kb * 64 + c4, *(const float4*)&Din[r * 64 + c4]);
    }
  } else if (ik) {
    float acc[4][4] = {};
    load_trans64(shA, 68, Din, 64, t);
    load_direct64(shB, 64, &Ms[(size_t)(kb * 64) * 256 + j * 64], 256, t);
    __syncthreads();
    gemm64<68, 64>(shA, shB, tr, tc, acc);
    __syncthreads();
#pragma unroll
    for (int mi = 0; mi < 4; ++mi) {
      float4 v = {acc[mi][0], acc[mi][1], acc[mi][2], acc[mi][3]};
      STORE(kb * 64 + tr * 4 + mi, j * 64 + tc * 4, v);
    }
  } else if (jk) {
    float acc[4][4] = {};
    load_trans64(shA, 68, &Ms[(size_t)(i * 64) * 256 + kb * 64], 256, t);
    load_direct64(shB, 64, Din, 64, t);
    __syncthreads();
    gemm64<68, 64>(shA, shB, tr, tc, acc);
    __syncthreads();
#pragma unroll
    for (int mi = 0; mi < 4; ++mi) {
      float4 v = {-acc[mi][0], -acc[mi][1], -acc[mi][2], -acc[mi][3]};
      STORE(i * 64 + tr * 4 + mi, kb * 64 + tc * 4, v);
    }
  } else {
    float acc[4][4] = {};
    load_trans64(shA, 68, Din, 64, t);
    load_direct64(shB, 64, &Ms[(size_t)(kb * 64) * 256 + j * 64], 256, t);
    load_trans64(shD, 68, &Ms[(size_t)(i * 64) * 256 + kb * 64], 256, t);
    __syncthreads();
    gemm64<68, 64>(shA, shB, tr, tc, acc);
    __syncthreads();
#pragma unroll
    for (int mi = 0; mi < 4; ++mi) {
      float4 v = {acc[mi][0], acc[mi][1], acc[mi][2], acc[mi][3]};
      *(float4*)&shB[(tr * 4 + mi) * 64 + tc * 4] = v;
    }
    __syncthreads();
    float acc2[4][4] = {};
    gemm64<68, 64>(shD, shB, tr, tc, acc2);
    bool la = (kb < 3) && (i == kb + 1) && (j == kb + 1);
    if (la) __syncthreads();
#pragma unroll
    for (int mi = 0; mi < 4; ++mi) {
      size_t off = (size_t)(i * 64 + tr * 4 + mi) * 256 + j * 64 + tc * 4;
      float4 old = *(const float4*)&Ms[off];
      float4 v = {old.x - acc2[mi][0], old.y - acc2[mi][1], old.z - acc2[mi][2], old.w - acc2[mi][3]};
      STORE(i * 64 + tr * 4 + mi, j * 64 + tc * 4, v);
      if (la) *(float4*)&shB[(tr * 4 + mi) * 64 + tc * 4] = v;
    }
    if (la) {
      __syncthreads();
      gj64<64>(shB, rowb, Dout, t);
    }
  }
}

// ================= k_tail: X = phi_q@Minv (jt-dedup) -> spread (coalesced) -> mu = X@G (LDS-staged) -> nll =================
__global__ __launch_bounds__(256) void k_tail(Params p) {
  __shared__ float Xlds[32 * 260];  // 33.3 KB
  __shared__ float Gs[64 * 68];     // 17.4 KB
  __shared__ float spf[32];
  __shared__ float ssdl[32];
  int b = blockIdx.x, qb = blockIdx.y * 32, t = threadIdx.x;
  int lane = t & 63, w = t >> 6;
  int klane = (lane >> 4) * 8;
  const float* Pq = p.phi_q + (size_t)b * 512 * 256;

  // a-frags for both 16-row strips (register-resident across all jt)
  short8 ah[2][8], al[2][8];
#pragma unroll
  for (int st = 0; st < 2; ++st) {
    int qlane = qb + st * 16 + (lane & 15);
#pragma unroll
    for (int k8 = 0; k8 < 8; ++k8) cvt8(&Pq[(size_t)qlane * 256 + k8 * 32 + klane], ah[st][k8], al[st][k8]);
  }

  // Phase A: each wave owns 4 jt tiles of IV, computes X columns for BOTH strips (IV read once per block)
  const unsigned short* Vh = p.IVh + (size_t)b * 65536;
  const unsigned short* Vl = p.IVl + (size_t)b * 65536;
  for (int jt = w * 4; jt < w * 4 + 4; ++jt) {
    int jrow = jt * 16 + (lane & 15);
    f32x4 acc0 = {}, acc1 = {};
#pragma unroll
    for (int k8 = 0; k8 < 8; ++k8) {
      short8 bh = ld8(Vh + (size_t)jrow * 256 + k8 * 32 + klane);
      short8 bl = ld8(Vl + (size_t)jrow * 256 + k8 * 32 + klane);
      acc0 = mfma3(ah[0][k8], al[0][k8], bh, bl, acc0);
      acc1 = mfma3(ah[1][k8], al[1][k8], bh, bl, acc1);
    }
    int xi = jt * 16 + (lane & 15);
#pragma unroll
    for (int r = 0; r < 4; ++r) {
      Xlds[((lane >> 4) * 4 + r) * 260 + xi] = acc0[r];
      Xlds[(16 + (lane >> 4) * 4 + r) * 260 + xi] = acc1[r];
    }
  }
  __syncthreads();

  // Phase B: spread = 1 + diag(X phi^T), coalesced phi reads
  {
    int q = t >> 3, c = t & 7;
    const float* Pqr = Pq + (size_t)(qb + q) * 256;
    float sp = 0.f;
#pragma unroll
    for (int i = c * 32; i < c * 32 + 32; i += 4) {
      float4 xv = *(const float4*)&Xlds[q * 260 + i];
      float4 pv = *(const float4*)&Pqr[i];
      sp += xv.x * pv.x + xv.y * pv.y + xv.z * pv.z + xv.w * pv.w;
    }
    sp += __shfl_xor(sp, 1);
    sp += __shfl_xor(sp, 2);
    sp += __shfl_xor(sp, 4);
    if (c == 0) spf[q] = 1.f + sp;
  }

  // Phase C: mu = X @ G^T with G staged in LDS (4 panels of 64 i-cols); thread (q, c) owns o = c + 8*oo
  {
    int q = t >> 3, c = t & 7;
    const float* Gr = p.RHST + (size_t)b * 16384;
    float accv[8] = {};
    for (int ip = 0; ip < 4; ++ip) {
      __syncthreads();
      int grr = t >> 2, gc = (t & 3) * 16;
#pragma unroll
      for (int m = 0; m < 4; ++m)
        *(float4*)&Gs[grr * 68 + gc + m * 4] = *(const float4*)&Gr[(size_t)grr * 256 + ip * 64 + gc + m * 4];
      __syncthreads();
#pragma unroll 2
      for (int i = 0; i < 64; i += 4) {
        float4 xv = *(const float4*)&Xlds[q * 260 + ip * 64 + i];
#pragma unroll
        for (int oo = 0; oo < 8; ++oo) {
          float4 gv = *(const float4*)&Gs[(c + oo * 8) * 68 + i];
          accv[oo] += xv.x * gv.x + xv.y * gv.y + xv.z * gv.z + xv.w * gv.w;
        }
      }
    }
    size_t qg = (size_t)b * 512 + qb + q;
    float ssd8 = 0.f;
#pragma unroll
    for (int oo = 0; oo < 8; ++oo) {
      int o = c + oo * 8;
      p.mu[qg * 64 + o] = accv[oo];
      float d = p.y_q[qg * 64 + o] - accv[oo];
      ssd8 += d * d;
    }
    ssd8 += __shfl_xor(ssd8, 1);
    ssd8 += __shfl_xor(ssd8, 2);
    ssd8 += __shfl_xor(ssd8, 4);
    if (c == 0) ssdl[q] = ssd8;
  }
  __syncthreads();

  // Phase D: nll partial + export spread
  if (w == 0) {
    float val = 0.f;
    if (t < 32) {
      float sp = spf[t];
      val = (64.f * (logf(sp) + LOG_SIG_EPS) + ssdl[t] / (sp * SIG_EPS)) * (1.0f / 16384.0f);
    }
#pragma unroll
    for (int off = 32; off; off >>= 1) val += __shfl_down(val, off);
    if (t == 0) atomicAdd(p.nll, val);
  }
  if (t < 32) p.spws[(size_t)b * 512 + qb + t] = spf[t];
}

// ================= k_sig: dedicated streaming sig fill (65536 blocks) =================
__global__ __launch_bounds__(256) void k_sig(const float* __restrict__ spws, float4* __restrict__ sig) {
  size_t idx = (size_t)blockIdx.x * 256 + threadIdx.x;
  int p4 = (int)(idx & 15);
  int o = (int)((idx >> 4) & 63);
  size_t bq = idx >> 10;
  float sv = spws[bq] * SIG_EPS;
  float4 v;
  v.x = (p4 * 4 + 0 == o) ? sv : 0.f;
  v.y = (p4 * 4 + 1 == o) ? sv : 0.f;
  v.z = (p4 * 4 + 2 == o) ? sv : 0.f;
  v.w = (p4 * 4 + 3 == o) ? sv : 0.f;
  sig[idx] = v;
}

extern "C" void kernel_launch(void* const* d_in, const int* in_sizes, int n_in, void* d_out, int out_size,
                              void* d_ws, size_t ws_size, hipStream_t stream) {
  float* ws = (float*)d_ws;
  unsigned short* u16b = (unsigned short*)(ws + WS_U16);
  float* out_mu = (float*)d_out;

  Params p;
  p.phi_s = (const float*)d_in[0];
  p.y_s = (const float*)d_in[1];
  p.phi_q = (const float*)d_in[2];
  p.y_q = (const float*)d_in[3];
  p.Km = (const float*)d_in[4];
  p.La = (const float*)d_in[5];
  p.Lm = ws + WS_L;
  p.T1 = ws + WS_T1;
  p.LKT = ws + WS_LKT;
  p.M0 = ws + WS_M0;
  p.M1 = ws + WS_M1;
  p.RHST = ws + WS_RHST;
  p.Dbuf = ws + WS_D;
  p.spws = ws + WS_SPF;
  p.PTh = u16b + U_PTH;
  p.PTl = u16b + U_PTL;
  p.YTh = u16b + U_YTH;
  p.YTl = u16b + U_YTL;
  p.IVh = u16b + U_IVH;
  p.IVl = u16b + U_IVL;
  p.mu = out_mu;
  p.sig = (float4*)(out_mu + OUT_MU_ELEMS);
  p.nll = out_mu + OUT_NLL_IDX;

  k_front<<<1300, 256, 0, stream>>>(p);
  k_gram<<<dim3(B, 15), 256, 0, stream>>>(p);
  k_st<<<dim3(B, 17), 256, 0, stream>>>(p, 0);
  k_st<<<dim3(B, 16), 256, 0, stream>>>(p, 1);
  k_st<<<dim3(B, 16), 256, 0, stream>>>(p, 2);
  k_st<<<dim3(B, 16), 256, 0, stream>>>(p, 3);
  k_tail<<<dim3(B, 16), 256, 0, stream>>>(p);
  k_sig<<<65536, 256, 0, stream>>>(p.spws, p.sig);
}